// Round 6
// baseline (285.546 us; speedup 1.0000x reference)
//
#include <hip/hip_runtime.h>

#define BATCH 8
#define S_LOG 9
#define SBUCKET 512          // nodes per bucket
#define KC 256               // max buckets (N <= 131071)
#define CB 512               // blocks for count/scatter
#define TTILE 2048           // edges per sort tile
#define EPT (TTILE / 256)    // edges per thread per tile
#define MD 4                 // deg sub-blocks per bucket
#define MA 4                 // accum sub-blocks per bucket

static inline size_t alignup(size_t x) { return (x + 255) & ~(size_t)255; }

// ---------------- pipeline kernels ----------------

// fused: blocks [0,CB) do bucket counting; blocks [CB, ...) transpose y -> yT[node][batch]
__global__ __launch_bounds__(256)
void count_transpose_kernel(const int* __restrict__ ei0, unsigned* __restrict__ counts,
                            const float* __restrict__ y, float* __restrict__ yT,
                            int E, int N) {
    __shared__ unsigned cnt[KC];
    int tid = threadIdx.x;
    if (blockIdx.x >= CB) {
        int n = (blockIdx.x - CB) * 256 + tid;
        if (n < N) {
            float v[BATCH];
#pragma unroll
            for (int b = 0; b < BATCH; ++b) v[b] = y[(size_t)b * N + n];
            float4* dst = (float4*)(yT + (size_t)n * BATCH);
            dst[0] = make_float4(v[0], v[1], v[2], v[3]);
            dst[1] = make_float4(v[4], v[5], v[6], v[7]);
        }
        return;
    }
    cnt[tid] = 0;
    __syncthreads();
    int chunk = (E + CB - 1) / CB;
    int lo = blockIdx.x * chunk;
    int hi = min(lo + chunk, E);
    for (int i = lo + tid; i < hi; i += 256)
        atomicAdd(&cnt[ei0[i] >> S_LOG], 1u);
    __syncthreads();
    counts[(size_t)blockIdx.x * KC + tid] = cnt[tid];   // coalesced
}

// one block, 256 threads: thread t owns bucket t
__global__ void scan_kernel(const unsigned* __restrict__ counts,
                            unsigned* __restrict__ base,
                            unsigned* __restrict__ bb, int E) {
    __shared__ unsigned sb[KC];
    int t = threadIdx.x;
    unsigned tot = 0;
    for (int b = 0; b < CB; ++b) tot += counts[(size_t)b * KC + t];  // coalesced
    sb[t] = tot;
    __syncthreads();
    for (int off = 1; off < KC; off <<= 1) {
        unsigned u = sb[t];
        unsigned a = (t >= off) ? sb[t - off] : 0u;
        __syncthreads();
        sb[t] = u + a;
        __syncthreads();
    }
    unsigned ex = sb[t] - tot;     // exclusive
    bb[t] = ex;
    if (t == KC - 1) bb[KC] = (unsigned)E;
    unsigned run = ex;
    for (int b = 0; b < CB; ++b) {
        base[(size_t)b * KC + t] = run;                 // coalesced
        run += counts[(size_t)b * KC + t];
    }
}

__global__ __launch_bounds__(256)
void scatter_kernel(const int* __restrict__ ei0, const int* __restrict__ ei1,
                    const float* __restrict__ dw, const float* __restrict__ gea,
                    const unsigned* __restrict__ base,
                    uint2* __restrict__ w0coef, unsigned* __restrict__ sg, int E) {
    __shared__ unsigned cursor[KC];
    __shared__ unsigned h[KC];
    __shared__ unsigned tstart[KC];
    __shared__ unsigned sb[KC];
    __shared__ uint4 staged[TTILE];      // 32 KB
    int tid = threadIdx.x;
    cursor[tid] = base[(size_t)blockIdx.x * KC + tid];
    int chunk = (E + CB - 1) / CB;
    int lo = blockIdx.x * chunk;
    int hi = min(lo + chunk, E);
    __syncthreads();

    for (int tileLo = lo; tileLo < hi; tileLo += TTILE) {
        int tn = min(TTILE, hi - tileLo);
        h[tid] = 0;
        __syncthreads();

        unsigned k_r[EPT], w0_r[EPT], sg_r[EPT], cf_r[EPT], rk_r[EPT];
#pragma unroll
        for (int j = 0; j < EPT; ++j) {
            int off = j * 256 + tid;
            k_r[j] = 0xFFFFFFFFu;
            if (off < tn) {
                int i = tileLo + off;
                int s0 = ei0[i];
                int s1 = ei1[i];
                unsigned k = (unsigned)s0 >> S_LOG;
                unsigned s0l = (unsigned)(s0 & (SBUCKET - 1));
                k_r[j] = k;
                w0_r[j] = (unsigned)s1 | (s0l << 17);
                unsigned gu = __float_as_uint(gea[i]);
                unsigned gb = (gu + 0x7FFFu + ((gu >> 16) & 1u)) >> 16;  // fp32->bf16 rne
                sg_r[j] = (s0l << 16) | gb;
                float sig = 1.0f / (1.0f + __expf(-dw[i]));
                cf_r[j] = __float_as_uint(sqrtf(sig));
            }
        }
#pragma unroll
        for (int j = 0; j < EPT; ++j)
            if (k_r[j] != 0xFFFFFFFFu) rk_r[j] = atomicAdd(&h[k_r[j]], 1u);
        __syncthreads();

        unsigned hv = h[tid];
        sb[tid] = hv;
        __syncthreads();
        for (int off = 1; off < KC; off <<= 1) {
            unsigned u = sb[tid];
            unsigned a = (tid >= off) ? sb[tid - off] : 0u;
            __syncthreads();
            sb[tid] = u + a;
            __syncthreads();
        }
        tstart[tid] = sb[tid] - hv;
        __syncthreads();

#pragma unroll
        for (int j = 0; j < EPT; ++j)
            if (k_r[j] != 0xFFFFFFFFu) {
                unsigned slot = tstart[k_r[j]] + rk_r[j];
                staged[slot] = make_uint4(w0_r[j], sg_r[j], cf_r[j], k_r[j]);
            }
        __syncthreads();

        // coalesced write-out: consecutive i -> consecutive global pos within bucket runs
        for (int i = tid; i < tn; i += 256) {
            uint4 u = staged[i];
            unsigned k = u.w;
            unsigned pos = cursor[k] + ((unsigned)i - tstart[k]);
            w0coef[pos] = make_uint2(u.x, u.z);
            sg[pos]     = u.y;
        }
        __syncthreads();
        cursor[tid] += h[tid];
        __syncthreads();
    }
}

// partial degree per bucket slice: grid (K, MD); 4B records (s0l<<16 | bf16(gea))
__global__ __launch_bounds__(256)
void pdeg_kernel(const unsigned* __restrict__ sg, const unsigned* __restrict__ bb,
                 float* __restrict__ pdeg, int Npad) {
    __shared__ float degl[SBUCKET];
    int k = blockIdx.x, m = blockIdx.y, tid = threadIdx.x;
    for (int i = tid; i < SBUCKET; i += 256) degl[i] = 0.0f;
    unsigned lo = bb[k], hi = bb[k + 1];
    unsigned cnt = hi - lo;
    unsigned slice = (cnt + MD - 1) / MD;
    unsigned slo = lo + m * slice;
    unsigned shi = min(slo + slice, hi);
    __syncthreads();
    unsigned i0 = slo + tid;
    unsigned c0 = 0, c1 = 0;
    bool v0 = i0 < shi, v1 = i0 + 256 < shi;
    if (v0) c0 = sg[i0];
    if (v1) c1 = sg[i0 + 256];
    while (v0) {
        unsigned ni = i0 + 512;
        unsigned n0 = 0, n1 = 0;
        bool nv0 = ni < shi, nv1 = ni + 256 < shi;
        if (nv0) n0 = sg[ni];
        if (nv1) n1 = sg[ni + 256];
        atomicAdd(&degl[c0 >> 16], __uint_as_float(c0 << 16));
        if (v1) atomicAdd(&degl[c1 >> 16], __uint_as_float(c1 << 16));
        v0 = nv0; v1 = nv1; c0 = n0; c1 = n1; i0 = ni;
    }
    __syncthreads();
    for (int i = tid; i < SBUCKET; i += 256)
        pdeg[(size_t)m * Npad + ((size_t)k << S_LOG) + i] = degl[i];
}

// reduce pdeg partials -> invd2g[Npad] = 1/deg^2
__global__ void invd2_kernel(const float* __restrict__ pdeg,
                             float* __restrict__ invd2g, int Npad) {
    int n = blockIdx.x * 256 + threadIdx.x;
    if (n < Npad) {
        float d = 0.0f;
#pragma unroll
        for (int m = 0; m < MD; ++m) d += pdeg[(size_t)m * Npad + n];
        invd2g[n] = 1.0f / (d * d);
    }
}

// main accumulation: grid (K, MA, 2) — each z-half handles 4 batches.
// software pipeline: records one pair-of-pairs ahead, gathers one pair ahead.
// processes 2 records/thread/iter, advances 512/iter.
__global__ __launch_bounds__(256)
void accum_kernel(const uint2* __restrict__ w0coef, const unsigned* __restrict__ bb,
                  const float* __restrict__ invd2g, const float* __restrict__ yT,
                  float* __restrict__ pout, int N, int Npad) {
    __shared__ float invd2[SBUCKET];
    __shared__ float y0l[4][SBUCKET];
    __shared__ float outl[4][SBUCKET];
    int k = blockIdx.x, m = blockIdx.y, tid = threadIdx.x;
    int b0 = blockIdx.z * 4;
    int n0 = k << S_LOG;

    for (int i = tid; i < SBUCKET; i += 256) invd2[i] = invd2g[n0 + i];
    for (int i = tid; i < 4 * SBUCKET; i += 256) ((float*)outl)[i] = 0.0f;
    int nvalid = min(SBUCKET, N - n0);
    for (int j = tid; j < nvalid; j += 256) {
        float4 v = *(const float4*)(yT + ((size_t)(n0 + j)) * BATCH + b0);
        y0l[0][j] = v.x; y0l[1][j] = v.y; y0l[2][j] = v.z; y0l[3][j] = v.w;
    }
    unsigned lo = bb[k], hi = bb[k + 1];
    unsigned cnt = hi - lo;
    unsigned slice = (cnt + MA - 1) / MA;
    unsigned slo = lo + m * slice;
    unsigned shi = min(slo + slice, hi);
    __syncthreads();

    unsigned i0 = slo + tid;
    uint2 c0 = make_uint2(0u, 0u), c1 = make_uint2(0u, 0u);
    uint2 d0 = make_uint2(0u, 0u), d1 = make_uint2(0u, 0u);
    float4 g0 = make_float4(0, 0, 0, 0), g1 = make_float4(0, 0, 0, 0);
    bool vc0 = i0 < shi, vc1 = i0 + 256 < shi;
    bool vd0 = i0 + 512 < shi, vd1 = i0 + 768 < shi;
    if (vc0) c0 = w0coef[i0];
    if (vc1) c1 = w0coef[i0 + 256];
    if (vc0) g0 = *(const float4*)(yT + (size_t)(c0.x & 0x1FFFFu) * BATCH + b0);
    if (vc1) g1 = *(const float4*)(yT + (size_t)(c1.x & 0x1FFFFu) * BATCH + b0);
    if (vd0) d0 = w0coef[i0 + 512];
    if (vd1) d1 = w0coef[i0 + 768];

    while (vc0) {
        float4 h0 = make_float4(0, 0, 0, 0), h1 = make_float4(0, 0, 0, 0);
        if (vd0) h0 = *(const float4*)(yT + (size_t)(d0.x & 0x1FFFFu) * BATCH + b0);
        if (vd1) h1 = *(const float4*)(yT + (size_t)(d1.x & 0x1FFFFu) * BATCH + b0);
        uint2 e0 = make_uint2(0u, 0u), e1 = make_uint2(0u, 0u);
        bool ve0 = i0 + 1024 < shi, ve1 = i0 + 1280 < shi;
        if (ve0) e0 = w0coef[i0 + 1024];
        if (ve1) e1 = w0coef[i0 + 1280];

        {
            unsigned s0l = c0.x >> 17;
            float c = __uint_as_float(c0.y) * invd2[s0l];
            float q0 = c * fmaxf(y0l[0][s0l] - g0.x, 0.0f);
            float q1 = c * fmaxf(y0l[1][s0l] - g0.y, 0.0f);
            float q2 = c * fmaxf(y0l[2][s0l] - g0.z, 0.0f);
            float q3 = c * fmaxf(y0l[3][s0l] - g0.w, 0.0f);
            if (q0 != 0.0f) atomicAdd(&outl[0][s0l], q0);
            if (q1 != 0.0f) atomicAdd(&outl[1][s0l], q1);
            if (q2 != 0.0f) atomicAdd(&outl[2][s0l], q2);
            if (q3 != 0.0f) atomicAdd(&outl[3][s0l], q3);
        }
        if (vc1) {
            unsigned s0l = c1.x >> 17;
            float c = __uint_as_float(c1.y) * invd2[s0l];
            float q0 = c * fmaxf(y0l[0][s0l] - g1.x, 0.0f);
            float q1 = c * fmaxf(y0l[1][s0l] - g1.y, 0.0f);
            float q2 = c * fmaxf(y0l[2][s0l] - g1.z, 0.0f);
            float q3 = c * fmaxf(y0l[3][s0l] - g1.w, 0.0f);
            if (q0 != 0.0f) atomicAdd(&outl[0][s0l], q0);
            if (q1 != 0.0f) atomicAdd(&outl[1][s0l], q1);
            if (q2 != 0.0f) atomicAdd(&outl[2][s0l], q2);
            if (q3 != 0.0f) atomicAdd(&outl[3][s0l], q3);
        }

        vc0 = vd0; vc1 = vd1; c0 = d0; c1 = d1; g0 = h0; g1 = h1;
        vd0 = ve0; vd1 = ve1; d0 = e0; d1 = e1;
        i0 += 512;
    }
    __syncthreads();

    for (int i = tid; i < 4 * SBUCKET; i += 256) {
        int b = i >> S_LOG;
        int j = i & (SBUCKET - 1);
        pout[((size_t)m * BATCH + b0 + b) * Npad + n0 + j] = outl[b][j];
    }
}

// out = 1 - sum_m pout : grid ((N+255)/256, BATCH)
__global__ void finalize_kernel(const float* __restrict__ pout,
                                float* __restrict__ out, int N, int Npad) {
    int n = blockIdx.x * blockDim.x + threadIdx.x;
    int b = blockIdx.y;
    if (n < N) {
        float s = 0.0f;
#pragma unroll
        for (int m = 0; m < MA; ++m)
            s += pout[((size_t)m * BATCH + b) * Npad + n];
        out[(size_t)b * N + n] = 1.0f - s;
    }
}

// ---------------- fallback (R1 path) ----------------

__global__ void fill_one_kernel(float* __restrict__ out, int n) {
    int i = blockIdx.x * blockDim.x + threadIdx.x;
    if (i < n) out[i] = 1.0f;
}

__global__ void deg_kernel(const float* __restrict__ gea,
                           const int* __restrict__ ei0,
                           float* __restrict__ deg, int E) {
    int e = blockIdx.x * blockDim.x + threadIdx.x;
    if (e < E) atomicAdd(&deg[ei0[e]], gea[e]);
}

__global__ void edge_kernel(const float* __restrict__ y,
                            const float* __restrict__ dw,
                            const int* __restrict__ ei0,
                            const int* __restrict__ ei1,
                            const float* __restrict__ deg,
                            float* __restrict__ out,
                            int E, int N) {
    int e = blockIdx.x * blockDim.x + threadIdx.x;
    if (e >= E) return;
    int s0 = ei0[e];
    int s1 = ei1[e];
    float d = deg[s0];
    float inv = 1.0f / (d * d);
    float sig = 1.0f / (1.0f + __expf(-dw[e]));
    float coef = sqrtf(sig) * inv;
#pragma unroll
    for (int b = 0; b < BATCH; ++b) {
        float y0 = y[(size_t)b * N + s0];
        float y1 = y[(size_t)b * N + s1];
        float gm = coef * fmaxf(y0 - y1, 0.0f);
        if (gm != 0.0f) atomicAdd(&out[(size_t)b * N + s0], -gm);
    }
}

// ---------------- launch ----------------

extern "C" void kernel_launch(void* const* d_in, const int* in_sizes, int n_in,
                              void* d_out, int out_size, void* d_ws, size_t ws_size,
                              hipStream_t stream) {
    const float* y   = (const float*)d_in[0];   // [B,N]
    const float* gea = (const float*)d_in[2];   // [E]
    const float* dw  = (const float*)d_in[3];   // [E]
    const int*   ei  = (const int*)d_in[4];     // [2,E]

    const int E = in_sizes[2];
    const int N = in_sizes[0] / BATCH;
    const int* ei0 = ei;
    const int* ei1 = ei + E;

    const int K = (N + SBUCKET - 1) >> S_LOG;
    const int Npad = K << S_LOG;

    size_t o_yT     = 0;
    size_t o_rcf    = o_yT     + alignup((size_t)N * BATCH * 4);
    size_t o_sg     = o_rcf    + alignup((size_t)E * 8);
    size_t o_counts = o_sg     + alignup((size_t)E * 4);
    size_t o_base   = o_counts + alignup((size_t)CB * KC * 4);
    size_t o_bb     = o_base   + alignup((size_t)CB * KC * 4);
    size_t o_pdeg   = o_bb     + alignup((size_t)(KC + 1) * 4);
    size_t o_inv    = o_pdeg   + alignup((size_t)MD * Npad * 4);
    size_t o_pout   = o_inv    + alignup((size_t)Npad * 4);
    size_t need     = o_pout   + alignup((size_t)MA * BATCH * Npad * 4);

    if (K <= KC && N <= 131071 && ws_size >= need) {
        char* w = (char*)d_ws;
        float*    yT     = (float*)(w + o_yT);
        uint2*    w0coef = (uint2*)(w + o_rcf);
        unsigned* sg     = (unsigned*)(w + o_sg);
        unsigned* counts = (unsigned*)(w + o_counts);
        unsigned* base   = (unsigned*)(w + o_base);
        unsigned* bb     = (unsigned*)(w + o_bb);
        float*    pdeg   = (float*)(w + o_pdeg);
        float*    invd2g = (float*)(w + o_inv);
        float*    pout   = (float*)(w + o_pout);

        int tb = (N + 255) / 256;
        count_transpose_kernel<<<CB + tb, 256, 0, stream>>>(ei0, counts, y, yT, E, N);
        scan_kernel<<<1, 256, 0, stream>>>(counts, base, bb, E);
        scatter_kernel<<<CB, 256, 0, stream>>>(ei0, ei1, dw, gea, base,
                                               w0coef, sg, E);
        pdeg_kernel<<<dim3(K, MD), 256, 0, stream>>>(sg, bb, pdeg, Npad);
        invd2_kernel<<<(Npad + 255) / 256, 256, 0, stream>>>(pdeg, invd2g, Npad);
        accum_kernel<<<dim3(K, MA, 2), 256, 0, stream>>>(w0coef, bb, invd2g, yT,
                                                         pout, N, Npad);
        finalize_kernel<<<dim3((N + 255) / 256, BATCH), 256, 0, stream>>>(
            pout, (float*)d_out, N, Npad);
    } else {
        float* deg = (float*)d_ws;
        hipMemsetAsync(deg, 0, (size_t)N * sizeof(float), stream);
        fill_one_kernel<<<(out_size + 255) / 256, 256, 0, stream>>>((float*)d_out, out_size);
        deg_kernel<<<(E + 255) / 256, 256, 0, stream>>>(gea, ei0, deg, E);
        edge_kernel<<<(E + 255) / 256, 256, 0, stream>>>(y, dw, ei0, ei1, deg,
                                                         (float*)d_out, E, N);
    }
}

// Round 7
// 276.313 us; speedup vs baseline: 1.0334x; 1.0334x over previous
//
#include <hip/hip_runtime.h>

#define BATCH 8
#define S_LOG 9
#define SBUCKET 512          // nodes per bucket
#define KC 256               // max buckets (N <= 131071)
#define CB 512               // blocks for count/scatter
#define TTILE 2048           // edges per sort tile
#define EPT (TTILE / 256)    // edges per thread per tile
#define MD 4                 // deg sub-blocks per bucket
#define MA 8                 // accum sub-blocks per bucket

static inline size_t alignup(size_t x) { return (x + 255) & ~(size_t)255; }

// ---------------- pipeline kernels ----------------

// fused: blocks [0,CB) do bucket counting; blocks [CB, ...) transpose y -> yT[node][batch]
__global__ __launch_bounds__(256)
void count_transpose_kernel(const int* __restrict__ ei0, unsigned* __restrict__ counts,
                            const float* __restrict__ y, float* __restrict__ yT,
                            int E, int N) {
    __shared__ unsigned cnt[KC];
    int tid = threadIdx.x;
    if (blockIdx.x >= CB) {
        int n = (blockIdx.x - CB) * 256 + tid;
        if (n < N) {
            float v[BATCH];
#pragma unroll
            for (int b = 0; b < BATCH; ++b) v[b] = y[(size_t)b * N + n];
            float4* dst = (float4*)(yT + (size_t)n * BATCH);
            dst[0] = make_float4(v[0], v[1], v[2], v[3]);
            dst[1] = make_float4(v[4], v[5], v[6], v[7]);
        }
        return;
    }
    cnt[tid] = 0;
    __syncthreads();
    int chunk = (E + CB - 1) / CB;
    int lo = blockIdx.x * chunk;
    int hi = min(lo + chunk, E);
    for (int i = lo + tid; i < hi; i += 256)
        atomicAdd(&cnt[ei0[i] >> S_LOG], 1u);
    __syncthreads();
    // counts layout: [bucket][block]
    counts[(size_t)tid * CB + blockIdx.x] = cnt[tid];
}

// scanA: one block — bucket totals (unrolled independent loads) + exclusive bucket bases bb
__global__ void scanA_kernel(const unsigned* __restrict__ counts,
                             unsigned* __restrict__ bb, int E) {
    __shared__ unsigned sb[KC];
    int t = threadIdx.x;
    unsigned acc[8] = {0, 0, 0, 0, 0, 0, 0, 0};
    const unsigned* row = counts + (size_t)t * CB;
#pragma unroll 1
    for (int b = 0; b < CB; b += 8) {
#pragma unroll
        for (int j = 0; j < 8; ++j) acc[j] += row[b + j];   // 8 independent chains
    }
    unsigned tot = 0;
#pragma unroll
    for (int j = 0; j < 8; ++j) tot += acc[j];
    sb[t] = tot;
    __syncthreads();
    for (int off = 1; off < KC; off <<= 1) {
        unsigned u = sb[t];
        unsigned a = (t >= off) ? sb[t - off] : 0u;
        __syncthreads();
        sb[t] = u + a;
        __syncthreads();
    }
    bb[t] = sb[t] - tot;       // exclusive
    if (t == KC - 1) bb[KC] = (unsigned)E;
}

// scanB: one block per bucket — exclusive prefix of counts[k][0..CB) + bb[k] -> base[k][b]
__global__ __launch_bounds__(256)
void scanB_kernel(const unsigned* __restrict__ counts, const unsigned* __restrict__ bb,
                  unsigned* __restrict__ base) {
    __shared__ unsigned s0[CB];
    __shared__ unsigned s1[CB];
    int k = blockIdx.x, tid = threadIdx.x;
    unsigned off0 = bb[k];
    // coalesced load of this bucket's 512 per-block counts
    s0[tid] = counts[(size_t)k * CB + tid];
    s0[tid + 256] = counts[(size_t)k * CB + tid + 256];
    __syncthreads();
    // Hillis-Steele inclusive scan over 512 (ping-pong buffers)
    unsigned* src = s0;
    unsigned* dst = s1;
    for (int off = 1; off < CB; off <<= 1) {
#pragma unroll
        for (int h = 0; h < 2; ++h) {
            int idx = tid + h * 256;
            unsigned v = src[idx];
            if (idx >= off) v += src[idx - off];
            dst[idx] = v;
        }
        __syncthreads();
        unsigned* tmp = src; src = dst; dst = tmp;
    }
    // exclusive + bucket base, coalesced store
#pragma unroll
    for (int h = 0; h < 2; ++h) {
        int idx = tid + h * 256;
        unsigned inc = src[idx];
        unsigned cntv = s0 == src ? s0[idx] : s0[idx];  // self count from original? need original counts
        // note: s0 may have been overwritten by ping-pong; recompute exclusive via inc - count
        base[(size_t)k * CB + idx] = off0 + inc - counts[(size_t)k * CB + idx];
    }
}

__global__ __launch_bounds__(256)
void scatter_kernel(const int* __restrict__ ei0, const int* __restrict__ ei1,
                    const float* __restrict__ dw, const float* __restrict__ gea,
                    const unsigned* __restrict__ base,
                    uint2* __restrict__ w0coef, unsigned* __restrict__ sg, int E) {
    __shared__ unsigned cursor[KC];
    __shared__ unsigned h[KC];
    __shared__ unsigned tstart[KC];
    __shared__ unsigned sb[KC];
    __shared__ uint4 staged[TTILE];      // 32 KB
    int tid = threadIdx.x;
    cursor[tid] = base[(size_t)tid * CB + blockIdx.x];   // [bucket][block] layout
    int chunk = (E + CB - 1) / CB;
    int lo = blockIdx.x * chunk;
    int hi = min(lo + chunk, E);
    __syncthreads();

    for (int tileLo = lo; tileLo < hi; tileLo += TTILE) {
        int tn = min(TTILE, hi - tileLo);
        h[tid] = 0;
        __syncthreads();

        unsigned k_r[EPT], w0_r[EPT], sg_r[EPT], cf_r[EPT], rk_r[EPT];
#pragma unroll
        for (int j = 0; j < EPT; ++j) {
            int off = j * 256 + tid;
            k_r[j] = 0xFFFFFFFFu;
            if (off < tn) {
                int i = tileLo + off;
                int s0v = ei0[i];
                int s1v = ei1[i];
                unsigned k = (unsigned)s0v >> S_LOG;
                unsigned s0l = (unsigned)(s0v & (SBUCKET - 1));
                k_r[j] = k;
                w0_r[j] = (unsigned)s1v | (s0l << 17);
                unsigned gu = __float_as_uint(gea[i]);
                unsigned gb = (gu + 0x7FFFu + ((gu >> 16) & 1u)) >> 16;  // fp32->bf16 rne
                sg_r[j] = (s0l << 16) | gb;
                float sig = 1.0f / (1.0f + __expf(-dw[i]));
                cf_r[j] = __float_as_uint(sqrtf(sig));
            }
        }
#pragma unroll
        for (int j = 0; j < EPT; ++j)
            if (k_r[j] != 0xFFFFFFFFu) rk_r[j] = atomicAdd(&h[k_r[j]], 1u);
        __syncthreads();

        unsigned hv = h[tid];
        sb[tid] = hv;
        __syncthreads();
        for (int off = 1; off < KC; off <<= 1) {
            unsigned u = sb[tid];
            unsigned a = (tid >= off) ? sb[tid - off] : 0u;
            __syncthreads();
            sb[tid] = u + a;
            __syncthreads();
        }
        tstart[tid] = sb[tid] - hv;
        __syncthreads();

#pragma unroll
        for (int j = 0; j < EPT; ++j)
            if (k_r[j] != 0xFFFFFFFFu) {
                unsigned slot = tstart[k_r[j]] + rk_r[j];
                staged[slot] = make_uint4(w0_r[j], sg_r[j], cf_r[j], k_r[j]);
            }
        __syncthreads();

        // coalesced write-out: consecutive i -> consecutive global pos within bucket runs
        for (int i = tid; i < tn; i += 256) {
            uint4 u = staged[i];
            unsigned k = u.w;
            unsigned pos = cursor[k] + ((unsigned)i - tstart[k]);
            w0coef[pos] = make_uint2(u.x, u.z);
            sg[pos]     = u.y;
        }
        __syncthreads();
        cursor[tid] += h[tid];
        __syncthreads();
    }
}

// partial degree per bucket slice: grid (K, MD); 4B records (s0l<<16 | bf16(gea))
__global__ __launch_bounds__(256)
void pdeg_kernel(const unsigned* __restrict__ sg, const unsigned* __restrict__ bb,
                 float* __restrict__ pdeg, int Npad) {
    __shared__ float degl[SBUCKET];
    int k = blockIdx.x, m = blockIdx.y, tid = threadIdx.x;
    for (int i = tid; i < SBUCKET; i += 256) degl[i] = 0.0f;
    unsigned lo = bb[k], hi = bb[k + 1];
    unsigned cnt = hi - lo;
    unsigned slice = (cnt + MD - 1) / MD;
    unsigned slo = lo + m * slice;
    unsigned shi = min(slo + slice, hi);
    __syncthreads();
    unsigned i0 = slo + tid;
    unsigned c0 = 0, c1 = 0;
    bool v0 = i0 < shi, v1 = i0 + 256 < shi;
    if (v0) c0 = sg[i0];
    if (v1) c1 = sg[i0 + 256];
    while (v0) {
        unsigned ni = i0 + 512;
        unsigned n0 = 0, n1 = 0;
        bool nv0 = ni < shi, nv1 = ni + 256 < shi;
        if (nv0) n0 = sg[ni];
        if (nv1) n1 = sg[ni + 256];
        atomicAdd(&degl[c0 >> 16], __uint_as_float(c0 << 16));
        if (v1) atomicAdd(&degl[c1 >> 16], __uint_as_float(c1 << 16));
        v0 = nv0; v1 = nv1; c0 = n0; c1 = n1; i0 = ni;
    }
    __syncthreads();
    for (int i = tid; i < SBUCKET; i += 256)
        pdeg[(size_t)m * Npad + ((size_t)k << S_LOG) + i] = degl[i];
}

// main accumulation: grid (K, MA, 2) — each z-half handles 4 batches.
// invd2 folded in (sums MD pdeg partials per node). depth-2 software pipeline.
__global__ __launch_bounds__(256)
void accum_kernel(const uint2* __restrict__ w0coef, const unsigned* __restrict__ bb,
                  const float* __restrict__ pdeg, const float* __restrict__ yT,
                  float* __restrict__ pout, int N, int Npad) {
    __shared__ float invd2[SBUCKET];
    __shared__ float y0l[4][SBUCKET];
    __shared__ float outl[4][SBUCKET];
    int k = blockIdx.x, m = blockIdx.y, tid = threadIdx.x;
    int b0 = blockIdx.z * 4;
    int n0 = k << S_LOG;

    for (int i = tid; i < SBUCKET; i += 256) {
        float d = 0.0f;
#pragma unroll
        for (int md = 0; md < MD; ++md)
            d += pdeg[(size_t)md * Npad + (size_t)n0 + i];
        invd2[i] = 1.0f / (d * d);
    }
    for (int i = tid; i < 4 * SBUCKET; i += 256) ((float*)outl)[i] = 0.0f;
    int nvalid = min(SBUCKET, N - n0);
    for (int j = tid; j < nvalid; j += 256) {
        float4 v = *(const float4*)(yT + ((size_t)(n0 + j)) * BATCH + b0);
        y0l[0][j] = v.x; y0l[1][j] = v.y; y0l[2][j] = v.z; y0l[3][j] = v.w;
    }
    unsigned lo = bb[k], hi = bb[k + 1];
    unsigned cnt = hi - lo;
    unsigned slice = (cnt + MA - 1) / MA;
    unsigned slo = lo + m * slice;
    unsigned shi = min(slo + slice, hi);
    __syncthreads();

    unsigned i0 = slo + tid;
    uint2 c0 = make_uint2(0u, 0u), c1 = make_uint2(0u, 0u);
    uint2 d0 = make_uint2(0u, 0u), d1 = make_uint2(0u, 0u);
    float4 g0 = make_float4(0, 0, 0, 0), g1 = make_float4(0, 0, 0, 0);
    bool vc0 = i0 < shi, vc1 = i0 + 256 < shi;
    bool vd0 = i0 + 512 < shi, vd1 = i0 + 768 < shi;
    if (vc0) c0 = w0coef[i0];
    if (vc1) c1 = w0coef[i0 + 256];
    if (vc0) g0 = *(const float4*)(yT + (size_t)(c0.x & 0x1FFFFu) * BATCH + b0);
    if (vc1) g1 = *(const float4*)(yT + (size_t)(c1.x & 0x1FFFFu) * BATCH + b0);
    if (vd0) d0 = w0coef[i0 + 512];
    if (vd1) d1 = w0coef[i0 + 768];

    while (vc0) {
        float4 h0 = make_float4(0, 0, 0, 0), h1 = make_float4(0, 0, 0, 0);
        if (vd0) h0 = *(const float4*)(yT + (size_t)(d0.x & 0x1FFFFu) * BATCH + b0);
        if (vd1) h1 = *(const float4*)(yT + (size_t)(d1.x & 0x1FFFFu) * BATCH + b0);
        uint2 e0 = make_uint2(0u, 0u), e1 = make_uint2(0u, 0u);
        bool ve0 = i0 + 1024 < shi, ve1 = i0 + 1280 < shi;
        if (ve0) e0 = w0coef[i0 + 1024];
        if (ve1) e1 = w0coef[i0 + 1280];

        {
            unsigned s0l = c0.x >> 17;
            float c = __uint_as_float(c0.y) * invd2[s0l];
            float q0 = c * fmaxf(y0l[0][s0l] - g0.x, 0.0f);
            float q1 = c * fmaxf(y0l[1][s0l] - g0.y, 0.0f);
            float q2 = c * fmaxf(y0l[2][s0l] - g0.z, 0.0f);
            float q3 = c * fmaxf(y0l[3][s0l] - g0.w, 0.0f);
            if (q0 != 0.0f) atomicAdd(&outl[0][s0l], q0);
            if (q1 != 0.0f) atomicAdd(&outl[1][s0l], q1);
            if (q2 != 0.0f) atomicAdd(&outl[2][s0l], q2);
            if (q3 != 0.0f) atomicAdd(&outl[3][s0l], q3);
        }
        if (vc1) {
            unsigned s0l = c1.x >> 17;
            float c = __uint_as_float(c1.y) * invd2[s0l];
            float q0 = c * fmaxf(y0l[0][s0l] - g1.x, 0.0f);
            float q1 = c * fmaxf(y0l[1][s0l] - g1.y, 0.0f);
            float q2 = c * fmaxf(y0l[2][s0l] - g1.z, 0.0f);
            float q3 = c * fmaxf(y0l[3][s0l] - g1.w, 0.0f);
            if (q0 != 0.0f) atomicAdd(&outl[0][s0l], q0);
            if (q1 != 0.0f) atomicAdd(&outl[1][s0l], q1);
            if (q2 != 0.0f) atomicAdd(&outl[2][s0l], q2);
            if (q3 != 0.0f) atomicAdd(&outl[3][s0l], q3);
        }

        vc0 = vd0; vc1 = vd1; c0 = d0; c1 = d1; g0 = h0; g1 = h1;
        vd0 = ve0; vd1 = ve1; d0 = e0; d1 = e1;
        i0 += 512;
    }
    __syncthreads();

    for (int i = tid; i < 4 * SBUCKET; i += 256) {
        int b = i >> S_LOG;
        int j = i & (SBUCKET - 1);
        pout[((size_t)m * BATCH + b0 + b) * Npad + n0 + j] = outl[b][j];
    }
}

// out = 1 - sum_m pout : grid ((N+255)/256, BATCH)
__global__ void finalize_kernel(const float* __restrict__ pout,
                                float* __restrict__ out, int N, int Npad) {
    int n = blockIdx.x * blockDim.x + threadIdx.x;
    int b = blockIdx.y;
    if (n < N) {
        float s = 0.0f;
#pragma unroll
        for (int m = 0; m < MA; ++m)
            s += pout[((size_t)m * BATCH + b) * Npad + n];
        out[(size_t)b * N + n] = 1.0f - s;
    }
}

// ---------------- fallback (R1 path) ----------------

__global__ void fill_one_kernel(float* __restrict__ out, int n) {
    int i = blockIdx.x * blockDim.x + threadIdx.x;
    if (i < n) out[i] = 1.0f;
}

__global__ void deg_kernel(const float* __restrict__ gea,
                           const int* __restrict__ ei0,
                           float* __restrict__ deg, int E) {
    int e = blockIdx.x * blockDim.x + threadIdx.x;
    if (e < E) atomicAdd(&deg[ei0[e]], gea[e]);
}

__global__ void edge_kernel(const float* __restrict__ y,
                            const float* __restrict__ dw,
                            const int* __restrict__ ei0,
                            const int* __restrict__ ei1,
                            const float* __restrict__ deg,
                            float* __restrict__ out,
                            int E, int N) {
    int e = blockIdx.x * blockDim.x + threadIdx.x;
    if (e >= E) return;
    int s0 = ei0[e];
    int s1 = ei1[e];
    float d = deg[s0];
    float inv = 1.0f / (d * d);
    float sig = 1.0f / (1.0f + __expf(-dw[e]));
    float coef = sqrtf(sig) * inv;
#pragma unroll
    for (int b = 0; b < BATCH; ++b) {
        float y0 = y[(size_t)b * N + s0];
        float y1 = y[(size_t)b * N + s1];
        float gm = coef * fmaxf(y0 - y1, 0.0f);
        if (gm != 0.0f) atomicAdd(&out[(size_t)b * N + s0], -gm);
    }
}

// ---------------- launch ----------------

extern "C" void kernel_launch(void* const* d_in, const int* in_sizes, int n_in,
                              void* d_out, int out_size, void* d_ws, size_t ws_size,
                              hipStream_t stream) {
    const float* y   = (const float*)d_in[0];   // [B,N]
    const float* gea = (const float*)d_in[2];   // [E]
    const float* dw  = (const float*)d_in[3];   // [E]
    const int*   ei  = (const int*)d_in[4];     // [2,E]

    const int E = in_sizes[2];
    const int N = in_sizes[0] / BATCH;
    const int* ei0 = ei;
    const int* ei1 = ei + E;

    const int K = (N + SBUCKET - 1) >> S_LOG;
    const int Npad = K << S_LOG;

    size_t o_yT     = 0;
    size_t o_rcf    = o_yT     + alignup((size_t)N * BATCH * 4);
    size_t o_sg     = o_rcf    + alignup((size_t)E * 8);
    size_t o_counts = o_sg     + alignup((size_t)E * 4);
    size_t o_base   = o_counts + alignup((size_t)CB * KC * 4);
    size_t o_bb     = o_base   + alignup((size_t)CB * KC * 4);
    size_t o_pdeg   = o_bb     + alignup((size_t)(KC + 1) * 4);
    size_t o_pout   = o_pdeg   + alignup((size_t)MD * Npad * 4);
    size_t need     = o_pout   + alignup((size_t)MA * BATCH * Npad * 4);

    if (K <= KC && N <= 131071 && ws_size >= need) {
        char* w = (char*)d_ws;
        float*    yT     = (float*)(w + o_yT);
        uint2*    w0coef = (uint2*)(w + o_rcf);
        unsigned* sg     = (unsigned*)(w + o_sg);
        unsigned* counts = (unsigned*)(w + o_counts);
        unsigned* base   = (unsigned*)(w + o_base);
        unsigned* bb     = (unsigned*)(w + o_bb);
        float*    pdeg   = (float*)(w + o_pdeg);
        float*    pout   = (float*)(w + o_pout);

        int tb = (N + 255) / 256;
        count_transpose_kernel<<<CB + tb, 256, 0, stream>>>(ei0, counts, y, yT, E, N);
        scanA_kernel<<<1, 256, 0, stream>>>(counts, bb, E);
        scanB_kernel<<<K, 256, 0, stream>>>(counts, bb, base);
        scatter_kernel<<<CB, 256, 0, stream>>>(ei0, ei1, dw, gea, base,
                                               w0coef, sg, E);
        pdeg_kernel<<<dim3(K, MD), 256, 0, stream>>>(sg, bb, pdeg, Npad);
        accum_kernel<<<dim3(K, MA, 2), 256, 0, stream>>>(w0coef, bb, pdeg, yT,
                                                         pout, N, Npad);
        finalize_kernel<<<dim3((N + 255) / 256, BATCH), 256, 0, stream>>>(
            pout, (float*)d_out, N, Npad);
    } else {
        float* deg = (float*)d_ws;
        hipMemsetAsync(deg, 0, (size_t)N * sizeof(float), stream);
        fill_one_kernel<<<(out_size + 255) / 256, 256, 0, stream>>>((float*)d_out, out_size);
        deg_kernel<<<(E + 255) / 256, 256, 0, stream>>>(gea, ei0, deg, E);
        edge_kernel<<<(E + 255) / 256, 256, 0, stream>>>(y, dw, ei0, ei1, deg,
                                                         (float*)d_out, E, N);
    }
}

// Round 8
// 244.580 us; speedup vs baseline: 1.1675x; 1.1297x over previous
//
#include <hip/hip_runtime.h>

#define BATCH 8
#define S_LOG 9
#define SBUCKET 512          // nodes per bucket
#define KC 256               // max buckets (N <= 131071)
#define CB 1024              // blocks for count/scatter
#define TTILE 2048           // edges per sort tile
#define EPT (TTILE / 256)    // edges per thread per tile
#define MD 4                 // deg sub-blocks per bucket
#define MA 8                 // accum sub-blocks per bucket

static inline size_t alignup(size_t x) { return (x + 255) & ~(size_t)255; }

__device__ __forceinline__ unsigned bf16hi(unsigned u) {
    // fp32 -> bf16 (rne), returned in LOW 16 bits
    return (u + 0x7FFFu + ((u >> 16) & 1u)) >> 16;
}

// ---------------- pipeline kernels ----------------

// fused: blocks [0,CB) do bucket counting; blocks [CB,...) transpose y -> yT[node][batch]
__global__ __launch_bounds__(256)
void count_transpose_kernel(const int* __restrict__ ei0, unsigned* __restrict__ counts,
                            const float* __restrict__ y, float* __restrict__ yT,
                            int E, int N) {
    __shared__ unsigned cnt[KC];
    int tid = threadIdx.x;
    if (blockIdx.x >= CB) {
        int n = (blockIdx.x - CB) * 256 + tid;
        if (n < N) {
            float v[BATCH];
#pragma unroll
            for (int b = 0; b < BATCH; ++b) v[b] = y[(size_t)b * N + n];
            float4* dst = (float4*)(yT + (size_t)n * BATCH);
            dst[0] = make_float4(v[0], v[1], v[2], v[3]);
            dst[1] = make_float4(v[4], v[5], v[6], v[7]);
        }
        return;
    }
    cnt[tid] = 0;
    __syncthreads();
    int chunk = (E + CB - 1) / CB;
    int lo = blockIdx.x * chunk;
    int hi = min(lo + chunk, E);
    for (int i = lo + tid; i < hi; i += 256)
        atomicAdd(&cnt[ei0[i] >> S_LOG], 1u);
    __syncthreads();
    // counts layout: [bucket][block]
    counts[(size_t)tid * CB + blockIdx.x] = cnt[tid];
}

// scanB1: one block per bucket — local exclusive prefix of counts[k][0..CB) -> base,
// and bucket total -> tot[k]. Fully coalesced uint4 loads/stores.
__global__ __launch_bounds__(256)
void scanB1_kernel(const unsigned* __restrict__ counts, unsigned* __restrict__ base,
                   unsigned* __restrict__ tot) {
    __shared__ unsigned ssum[256];
    int k = blockIdx.x, tid = threadIdx.x;
    const uint4* row4 = (const uint4*)(counts + (size_t)k * CB);
    uint4 v = row4[tid];
    unsigned lsum = v.x + v.y + v.z + v.w;
    ssum[tid] = lsum;
    __syncthreads();
    for (int off = 1; off < 256; off <<= 1) {
        unsigned u = ssum[tid];
        unsigned a = (tid >= off) ? ssum[tid - off] : 0u;
        __syncthreads();
        ssum[tid] = u + a;
        __syncthreads();
    }
    unsigned ex = ssum[tid] - lsum;
    if (tid == 255) tot[k] = ssum[255];
    uint4 o;
    o.x = ex;
    o.y = ex + v.x;
    o.z = o.y + v.y;
    o.w = o.z + v.z;
    ((uint4*)(base + (size_t)k * CB))[tid] = o;
}

// scanC: one block — exclusive scan of bucket totals -> bb[0..KC], bb[KC]=E
__global__ void scanC_kernel(const unsigned* __restrict__ tot,
                             unsigned* __restrict__ bb, int E, int K) {
    __shared__ unsigned sb[KC];
    int t = threadIdx.x;
    unsigned v = (t < K) ? tot[t] : 0u;
    sb[t] = v;
    __syncthreads();
    for (int off = 1; off < KC; off <<= 1) {
        unsigned u = sb[t];
        unsigned a = (t >= off) ? sb[t - off] : 0u;
        __syncthreads();
        sb[t] = u + a;
        __syncthreads();
    }
    bb[t] = sb[t] - v;
    if (t == KC - 1) bb[KC] = (unsigned)E;
}

// scatter: bucket-sort edges into w0coef records.
// record: .x = s1 | s0l<<17 ; .y = bf16(coef)<<16 | bf16(gea)
__global__ __launch_bounds__(256)
void scatter_kernel(const int* __restrict__ ei0, const int* __restrict__ ei1,
                    const float* __restrict__ dw, const float* __restrict__ gea,
                    const unsigned* __restrict__ base, const unsigned* __restrict__ bb,
                    uint2* __restrict__ w0coef, int E) {
    __shared__ unsigned cursor[KC];
    __shared__ unsigned h[KC];
    __shared__ unsigned tstart[KC];
    __shared__ unsigned sb[KC];
    __shared__ uint2 srec[TTILE];            // 16 KB
    __shared__ unsigned char skey[TTILE];    // 2 KB
    int tid = threadIdx.x;
    cursor[tid] = base[(size_t)tid * CB + blockIdx.x] + bb[tid];
    int chunk = (E + CB - 1) / CB;
    int lo = blockIdx.x * chunk;
    int hi = min(lo + chunk, E);
    __syncthreads();

    for (int tileLo = lo; tileLo < hi; tileLo += TTILE) {
        int tn = min(TTILE, hi - tileLo);
        h[tid] = 0;
        __syncthreads();

        unsigned k_r[EPT], w0_r[EPT], pk_r[EPT], rk_r[EPT];
#pragma unroll
        for (int j = 0; j < EPT; ++j) {
            int off = j * 256 + tid;
            k_r[j] = 0xFFFFFFFFu;
            if (off < tn) {
                int i = tileLo + off;
                int s0v = ei0[i];
                int s1v = ei1[i];
                unsigned k = (unsigned)s0v >> S_LOG;
                unsigned s0l = (unsigned)(s0v & (SBUCKET - 1));
                k_r[j] = k;
                w0_r[j] = (unsigned)s1v | (s0l << 17);
                float sig = 1.0f / (1.0f + __expf(-dw[i]));
                unsigned cf = __float_as_uint(sqrtf(sig));
                unsigned gu = __float_as_uint(gea[i]);
                pk_r[j] = (bf16hi(cf) << 16) | bf16hi(gu);
            }
        }
#pragma unroll
        for (int j = 0; j < EPT; ++j)
            if (k_r[j] != 0xFFFFFFFFu) rk_r[j] = atomicAdd(&h[k_r[j]], 1u);
        __syncthreads();

        unsigned hv = h[tid];
        sb[tid] = hv;
        __syncthreads();
        for (int off = 1; off < KC; off <<= 1) {
            unsigned u = sb[tid];
            unsigned a = (tid >= off) ? sb[tid - off] : 0u;
            __syncthreads();
            sb[tid] = u + a;
            __syncthreads();
        }
        tstart[tid] = sb[tid] - hv;
        __syncthreads();

#pragma unroll
        for (int j = 0; j < EPT; ++j)
            if (k_r[j] != 0xFFFFFFFFu) {
                unsigned slot = tstart[k_r[j]] + rk_r[j];
                srec[slot] = make_uint2(w0_r[j], pk_r[j]);
                skey[slot] = (unsigned char)k_r[j];
            }
        __syncthreads();

        // coalesced write-out: consecutive i -> consecutive global pos within bucket runs
        for (int i = tid; i < tn; i += 256) {
            uint2 u = srec[i];
            unsigned k = skey[i];
            unsigned pos = cursor[k] + ((unsigned)i - tstart[k]);
            w0coef[pos] = u;
        }
        __syncthreads();
        cursor[tid] += h[tid];
        __syncthreads();
    }
}

// partial degree per bucket slice: grid (K, MD); gea = bf16 in record .y low half
__global__ __launch_bounds__(256)
void pdeg_kernel(const uint2* __restrict__ w0coef, const unsigned* __restrict__ bb,
                 float* __restrict__ pdeg, int Npad) {
    __shared__ float degl[SBUCKET];
    int k = blockIdx.x, m = blockIdx.y, tid = threadIdx.x;
    for (int i = tid; i < SBUCKET; i += 256) degl[i] = 0.0f;
    unsigned lo = bb[k], hi = bb[k + 1];
    unsigned cnt = hi - lo;
    unsigned slice = (cnt + MD - 1) / MD;
    unsigned slo = lo + m * slice;
    unsigned shi = min(slo + slice, hi);
    __syncthreads();
    unsigned i0 = slo + tid;
    uint2 c0 = make_uint2(0u, 0u), c1 = make_uint2(0u, 0u);
    bool v0 = i0 < shi, v1 = i0 + 256 < shi;
    if (v0) c0 = w0coef[i0];
    if (v1) c1 = w0coef[i0 + 256];
    while (v0) {
        unsigned ni = i0 + 512;
        uint2 n0 = make_uint2(0u, 0u), n1 = make_uint2(0u, 0u);
        bool nv0 = ni < shi, nv1 = ni + 256 < shi;
        if (nv0) n0 = w0coef[ni];
        if (nv1) n1 = w0coef[ni + 256];
        atomicAdd(&degl[c0.x >> 17], __uint_as_float(c0.y << 16));
        if (v1) atomicAdd(&degl[c1.x >> 17], __uint_as_float(c1.y << 16));
        v0 = nv0; v1 = nv1; c0 = n0; c1 = n1; i0 = ni;
    }
    __syncthreads();
    for (int i = tid; i < SBUCKET; i += 256)
        pdeg[(size_t)m * Npad + ((size_t)k << S_LOG) + i] = degl[i];
}

// reduce pdeg partials -> invd2g[Npad] = 1/deg^2
__global__ void invd2_kernel(const float* __restrict__ pdeg,
                             float* __restrict__ invd2g, int Npad) {
    int n = blockIdx.x * 256 + threadIdx.x;
    if (n < Npad) {
        float d = 0.0f;
#pragma unroll
        for (int m = 0; m < MD; ++m) d += pdeg[(size_t)m * Npad + n];
        invd2g[n] = 1.0f / (d * d);
    }
}

// main accumulation: grid (K, MA, 2) — each z-half handles 4 batches.
// depth-3 record prefetch, depth-2 gather prefetch; padded LDS rows (bank conflicts).
__global__ __launch_bounds__(256)
void accum_kernel(const uint2* __restrict__ w0coef, const unsigned* __restrict__ bb,
                  const float* __restrict__ invd2g, const float* __restrict__ yT,
                  float* __restrict__ pout, int N, int Npad) {
    __shared__ float invd2[SBUCKET];
    __shared__ float y0l[4][SBUCKET + 1];
    __shared__ float outl[4][SBUCKET + 1];
    int k = blockIdx.x, m = blockIdx.y, tid = threadIdx.x;
    int b0 = blockIdx.z * 4;
    int n0 = k << S_LOG;

    for (int i = tid; i < SBUCKET; i += 256) invd2[i] = invd2g[n0 + i];
    for (int i = tid; i < 4 * (SBUCKET + 1); i += 256) ((float*)outl)[i] = 0.0f;
    int nvalid = min(SBUCKET, N - n0);
    for (int j = tid; j < nvalid; j += 256) {
        float4 v = *(const float4*)(yT + ((size_t)(n0 + j)) * BATCH + b0);
        y0l[0][j] = v.x; y0l[1][j] = v.y; y0l[2][j] = v.z; y0l[3][j] = v.w;
    }
    unsigned lo = bb[k], hi = bb[k + 1];
    unsigned cnt = hi - lo;
    unsigned slice = (cnt + MA - 1) / MA;
    unsigned slo = lo + m * slice;
    unsigned shi = min(slo + slice, hi);
    __syncthreads();

    unsigned i0 = slo + tid;
    uint2 c0 = make_uint2(0u, 0u), c1 = c0, d0 = c0, d1 = c0, e0 = c0, e1 = c0;
    float4 zf = make_float4(0, 0, 0, 0);
    float4 g0 = zf, g1 = zf, h0 = zf, h1 = zf;
    bool vc0 = i0 < shi,        vc1 = i0 + 256 < shi;
    bool vd0 = i0 + 512 < shi,  vd1 = i0 + 768 < shi;
    bool ve0 = i0 + 1024 < shi, ve1 = i0 + 1280 < shi;
    if (vc0) c0 = w0coef[i0];
    if (vc1) c1 = w0coef[i0 + 256];
    if (vd0) d0 = w0coef[i0 + 512];
    if (vd1) d1 = w0coef[i0 + 768];
    if (ve0) e0 = w0coef[i0 + 1024];
    if (ve1) e1 = w0coef[i0 + 1280];
    if (vc0) g0 = *(const float4*)(yT + (size_t)(c0.x & 0x1FFFFu) * BATCH + b0);
    if (vc1) g1 = *(const float4*)(yT + (size_t)(c1.x & 0x1FFFFu) * BATCH + b0);
    if (vd0) h0 = *(const float4*)(yT + (size_t)(d0.x & 0x1FFFFu) * BATCH + b0);
    if (vd1) h1 = *(const float4*)(yT + (size_t)(d1.x & 0x1FFFFu) * BATCH + b0);

    while (vc0) {
        // issue gathers for e-records (used 2 iters from now)
        float4 p0 = zf, p1 = zf;
        if (ve0) p0 = *(const float4*)(yT + (size_t)(e0.x & 0x1FFFFu) * BATCH + b0);
        if (ve1) p1 = *(const float4*)(yT + (size_t)(e1.x & 0x1FFFFu) * BATCH + b0);
        // load records 3 iters ahead
        uint2 f0 = make_uint2(0u, 0u), f1 = make_uint2(0u, 0u);
        bool vf0 = i0 + 1536 < shi, vf1 = i0 + 1792 < shi;
        if (vf0) f0 = w0coef[i0 + 1536];
        if (vf1) f1 = w0coef[i0 + 1792];

        {
            unsigned s0l = c0.x >> 17;
            float c = __uint_as_float(c0.y & 0xFFFF0000u) * invd2[s0l];
            float q0 = c * fmaxf(y0l[0][s0l] - g0.x, 0.0f);
            float q1 = c * fmaxf(y0l[1][s0l] - g0.y, 0.0f);
            float q2 = c * fmaxf(y0l[2][s0l] - g0.z, 0.0f);
            float q3 = c * fmaxf(y0l[3][s0l] - g0.w, 0.0f);
            if (q0 != 0.0f) atomicAdd(&outl[0][s0l], q0);
            if (q1 != 0.0f) atomicAdd(&outl[1][s0l], q1);
            if (q2 != 0.0f) atomicAdd(&outl[2][s0l], q2);
            if (q3 != 0.0f) atomicAdd(&outl[3][s0l], q3);
        }
        if (vc1) {
            unsigned s0l = c1.x >> 17;
            float c = __uint_as_float(c1.y & 0xFFFF0000u) * invd2[s0l];
            float q0 = c * fmaxf(y0l[0][s0l] - g1.x, 0.0f);
            float q1 = c * fmaxf(y0l[1][s0l] - g1.y, 0.0f);
            float q2 = c * fmaxf(y0l[2][s0l] - g1.z, 0.0f);
            float q3 = c * fmaxf(y0l[3][s0l] - g1.w, 0.0f);
            if (q0 != 0.0f) atomicAdd(&outl[0][s0l], q0);
            if (q1 != 0.0f) atomicAdd(&outl[1][s0l], q1);
            if (q2 != 0.0f) atomicAdd(&outl[2][s0l], q2);
            if (q3 != 0.0f) atomicAdd(&outl[3][s0l], q3);
        }

        c0 = d0; c1 = d1; d0 = e0; d1 = e1; e0 = f0; e1 = f1;
        g0 = h0; g1 = h1; h0 = p0; h1 = p1;
        vc0 = vd0; vc1 = vd1; vd0 = ve0; vd1 = ve1; ve0 = vf0; ve1 = vf1;
        i0 += 512;
    }
    __syncthreads();

    for (int i = tid; i < 4 * SBUCKET; i += 256) {
        int b = i >> S_LOG;
        int j = i & (SBUCKET - 1);
        pout[((size_t)m * BATCH + b0 + b) * Npad + n0 + j] = outl[b][j];
    }
}

// out = 1 - sum_m pout : grid ((N+255)/256, BATCH)
__global__ void finalize_kernel(const float* __restrict__ pout,
                                float* __restrict__ out, int N, int Npad) {
    int n = blockIdx.x * blockDim.x + threadIdx.x;
    int b = blockIdx.y;
    if (n < N) {
        float s = 0.0f;
#pragma unroll
        for (int m = 0; m < MA; ++m)
            s += pout[((size_t)m * BATCH + b) * Npad + n];
        out[(size_t)b * N + n] = 1.0f - s;
    }
}

// ---------------- fallback (R1 path) ----------------

__global__ void fill_one_kernel(float* __restrict__ out, int n) {
    int i = blockIdx.x * blockDim.x + threadIdx.x;
    if (i < n) out[i] = 1.0f;
}

__global__ void deg_kernel(const float* __restrict__ gea,
                           const int* __restrict__ ei0,
                           float* __restrict__ deg, int E) {
    int e = blockIdx.x * blockDim.x + threadIdx.x;
    if (e < E) atomicAdd(&deg[ei0[e]], gea[e]);
}

__global__ void edge_kernel(const float* __restrict__ y,
                            const float* __restrict__ dw,
                            const int* __restrict__ ei0,
                            const int* __restrict__ ei1,
                            const float* __restrict__ deg,
                            float* __restrict__ out,
                            int E, int N) {
    int e = blockIdx.x * blockDim.x + threadIdx.x;
    if (e >= E) return;
    int s0 = ei0[e];
    int s1 = ei1[e];
    float d = deg[s0];
    float inv = 1.0f / (d * d);
    float sig = 1.0f / (1.0f + __expf(-dw[e]));
    float coef = sqrtf(sig) * inv;
#pragma unroll
    for (int b = 0; b < BATCH; ++b) {
        float y0 = y[(size_t)b * N + s0];
        float y1 = y[(size_t)b * N + s1];
        float gm = coef * fmaxf(y0 - y1, 0.0f);
        if (gm != 0.0f) atomicAdd(&out[(size_t)b * N + s0], -gm);
    }
}

// ---------------- launch ----------------

extern "C" void kernel_launch(void* const* d_in, const int* in_sizes, int n_in,
                              void* d_out, int out_size, void* d_ws, size_t ws_size,
                              hipStream_t stream) {
    const float* y   = (const float*)d_in[0];   // [B,N]
    const float* gea = (const float*)d_in[2];   // [E]
    const float* dw  = (const float*)d_in[3];   // [E]
    const int*   ei  = (const int*)d_in[4];     // [2,E]

    const int E = in_sizes[2];
    const int N = in_sizes[0] / BATCH;
    const int* ei0 = ei;
    const int* ei1 = ei + E;

    const int K = (N + SBUCKET - 1) >> S_LOG;
    const int Npad = K << S_LOG;

    size_t o_yT     = 0;
    size_t o_rcf    = o_yT     + alignup((size_t)N * BATCH * 4);
    size_t o_counts = o_rcf    + alignup((size_t)E * 8);
    size_t o_base   = o_counts + alignup((size_t)KC * CB * 4);
    size_t o_tot    = o_base   + alignup((size_t)KC * CB * 4);
    size_t o_bb     = o_tot    + alignup((size_t)KC * 4);
    size_t o_pdeg   = o_bb     + alignup((size_t)(KC + 1) * 4);
    size_t o_inv    = o_pdeg   + alignup((size_t)MD * Npad * 4);
    size_t o_pout   = o_inv    + alignup((size_t)Npad * 4);
    size_t need     = o_pout   + alignup((size_t)MA * BATCH * Npad * 4);

    if (K <= KC && N <= 131071 && ws_size >= need) {
        char* w = (char*)d_ws;
        float*    yT     = (float*)(w + o_yT);
        uint2*    w0coef = (uint2*)(w + o_rcf);
        unsigned* counts = (unsigned*)(w + o_counts);
        unsigned* base   = (unsigned*)(w + o_base);
        unsigned* tot    = (unsigned*)(w + o_tot);
        unsigned* bb     = (unsigned*)(w + o_bb);
        float*    pdeg   = (float*)(w + o_pdeg);
        float*    invd2g = (float*)(w + o_inv);
        float*    pout   = (float*)(w + o_pout);

        int tb = (N + 255) / 256;
        count_transpose_kernel<<<CB + tb, 256, 0, stream>>>(ei0, counts, y, yT, E, N);
        scanB1_kernel<<<K, 256, 0, stream>>>(counts, base, tot);
        scanC_kernel<<<1, KC, 0, stream>>>(tot, bb, E, K);
        scatter_kernel<<<CB, 256, 0, stream>>>(ei0, ei1, dw, gea, base, bb,
                                               w0coef, E);
        pdeg_kernel<<<dim3(K, MD), 256, 0, stream>>>(w0coef, bb, pdeg, Npad);
        invd2_kernel<<<(Npad + 255) / 256, 256, 0, stream>>>(pdeg, invd2g, Npad);
        accum_kernel<<<dim3(K, MA, 2), 256, 0, stream>>>(w0coef, bb, invd2g, yT,
                                                         pout, N, Npad);
        finalize_kernel<<<dim3((N + 255) / 256, BATCH), 256, 0, stream>>>(
            pout, (float*)d_out, N, Npad);
    } else {
        float* deg = (float*)d_ws;
        hipMemsetAsync(deg, 0, (size_t)N * sizeof(float), stream);
        fill_one_kernel<<<(out_size + 255) / 256, 256, 0, stream>>>((float*)d_out, out_size);
        deg_kernel<<<(E + 255) / 256, 256, 0, stream>>>(gea, ei0, deg, E);
        edge_kernel<<<(E + 255) / 256, 256, 0, stream>>>(y, dw, ei0, ei1, deg,
                                                         (float*)d_out, E, N);
    }
}

// Round 9
// 243.916 us; speedup vs baseline: 1.1707x; 1.0027x over previous
//
#include <hip/hip_runtime.h>

#define BATCH 8
#define S_LOG 9
#define SBUCKET 512          // nodes per bucket
#define KC 256               // max buckets (N <= 131071)
#define CB 1024              // blocks for count/scatter
#define TTILE 2048           // edges per sort tile
#define EPT (TTILE / 256)    // edges per thread per tile
#define MD 4                 // deg sub-blocks per bucket
#define MA 8                 // accum sub-blocks per bucket

static inline size_t alignup(size_t x) { return (x + 255) & ~(size_t)255; }

__device__ __forceinline__ unsigned bf16hi(unsigned u) {
    // fp32 -> bf16 (rne), returned in LOW 16 bits
    return (u + 0x7FFFu + ((u >> 16) & 1u)) >> 16;
}

// ---------------- pipeline kernels ----------------

// fused: blocks [0,CB) bucket-count; blocks [CB,...) transpose y -> yT[node] = 8 bf16 (uint4)
__global__ __launch_bounds__(256)
void count_transpose_kernel(const int* __restrict__ ei0, unsigned* __restrict__ counts,
                            const float* __restrict__ y, uint4* __restrict__ yT,
                            int E, int N, int Npad) {
    __shared__ unsigned cnt[KC];
    int tid = threadIdx.x;
    if (blockIdx.x >= CB) {
        int n = (blockIdx.x - CB) * 256 + tid;
        if (n < Npad) {
            uint4 o = make_uint4(0u, 0u, 0u, 0u);
            if (n < N) {
                unsigned p[8];
#pragma unroll
                for (int b = 0; b < BATCH; ++b)
                    p[b] = bf16hi(__float_as_uint(y[(size_t)b * N + n]));
                o = make_uint4(p[0] | (p[1] << 16), p[2] | (p[3] << 16),
                               p[4] | (p[5] << 16), p[6] | (p[7] << 16));
            }
            yT[n] = o;
        }
        return;
    }
    cnt[tid] = 0;
    __syncthreads();
    int chunk = (E + CB - 1) / CB;
    int lo = blockIdx.x * chunk;
    int hi = min(lo + chunk, E);
    for (int i = lo + tid; i < hi; i += 256)
        atomicAdd(&cnt[ei0[i] >> S_LOG], 1u);
    __syncthreads();
    counts[(size_t)tid * CB + blockIdx.x] = cnt[tid];   // [bucket][block]
}

// scanB1: one block per bucket — local exclusive prefix of counts[k][0..CB) -> base,
// and bucket total -> tot[k]. Fully coalesced uint4 loads/stores.
__global__ __launch_bounds__(256)
void scanB1_kernel(const unsigned* __restrict__ counts, unsigned* __restrict__ base,
                   unsigned* __restrict__ tot) {
    __shared__ unsigned ssum[256];
    int k = blockIdx.x, tid = threadIdx.x;
    const uint4* row4 = (const uint4*)(counts + (size_t)k * CB);
    uint4 v = row4[tid];
    unsigned lsum = v.x + v.y + v.z + v.w;
    ssum[tid] = lsum;
    __syncthreads();
    for (int off = 1; off < 256; off <<= 1) {
        unsigned u = ssum[tid];
        unsigned a = (tid >= off) ? ssum[tid - off] : 0u;
        __syncthreads();
        ssum[tid] = u + a;
        __syncthreads();
    }
    unsigned ex = ssum[tid] - lsum;
    if (tid == 255) tot[k] = ssum[255];
    uint4 o;
    o.x = ex;
    o.y = ex + v.x;
    o.z = o.y + v.y;
    o.w = o.z + v.z;
    ((uint4*)(base + (size_t)k * CB))[tid] = o;
}

// scanC: one block — exclusive scan of bucket totals -> bb[0..KC], bb[KC]=E
__global__ void scanC_kernel(const unsigned* __restrict__ tot,
                             unsigned* __restrict__ bb, int E, int K) {
    __shared__ unsigned sb[KC];
    int t = threadIdx.x;
    unsigned v = (t < K) ? tot[t] : 0u;
    sb[t] = v;
    __syncthreads();
    for (int off = 1; off < KC; off <<= 1) {
        unsigned u = sb[t];
        unsigned a = (t >= off) ? sb[t - off] : 0u;
        __syncthreads();
        sb[t] = u + a;
        __syncthreads();
    }
    bb[t] = sb[t] - v;
    if (t == KC - 1) bb[KC] = (unsigned)E;
}

// scatter: bucket-sort edges into w0coef records.
// record: .x = s1 | s0l<<17 ; .y = bf16(coef)<<16 | bf16(gea)
__global__ __launch_bounds__(256)
void scatter_kernel(const int* __restrict__ ei0, const int* __restrict__ ei1,
                    const float* __restrict__ dw, const float* __restrict__ gea,
                    const unsigned* __restrict__ base, const unsigned* __restrict__ bb,
                    uint2* __restrict__ w0coef, int E) {
    __shared__ unsigned cursor[KC];
    __shared__ unsigned h[KC];
    __shared__ unsigned tstart[KC];
    __shared__ unsigned sb[KC];
    __shared__ uint2 srec[TTILE];            // 16 KB
    __shared__ unsigned char skey[TTILE];    // 2 KB
    int tid = threadIdx.x;
    cursor[tid] = base[(size_t)tid * CB + blockIdx.x] + bb[tid];
    int chunk = (E + CB - 1) / CB;
    int lo = blockIdx.x * chunk;
    int hi = min(lo + chunk, E);
    __syncthreads();

    for (int tileLo = lo; tileLo < hi; tileLo += TTILE) {
        int tn = min(TTILE, hi - tileLo);
        h[tid] = 0;
        __syncthreads();

        unsigned k_r[EPT], w0_r[EPT], pk_r[EPT], rk_r[EPT];
#pragma unroll
        for (int j = 0; j < EPT; ++j) {
            int off = j * 256 + tid;
            k_r[j] = 0xFFFFFFFFu;
            if (off < tn) {
                int i = tileLo + off;
                int s0v = ei0[i];
                int s1v = ei1[i];
                unsigned k = (unsigned)s0v >> S_LOG;
                unsigned s0l = (unsigned)(s0v & (SBUCKET - 1));
                k_r[j] = k;
                w0_r[j] = (unsigned)s1v | (s0l << 17);
                float sig = 1.0f / (1.0f + __expf(-dw[i]));
                unsigned cf = __float_as_uint(sqrtf(sig));
                unsigned gu = __float_as_uint(gea[i]);
                pk_r[j] = (bf16hi(cf) << 16) | bf16hi(gu);
            }
        }
#pragma unroll
        for (int j = 0; j < EPT; ++j)
            if (k_r[j] != 0xFFFFFFFFu) rk_r[j] = atomicAdd(&h[k_r[j]], 1u);
        __syncthreads();

        unsigned hv = h[tid];
        sb[tid] = hv;
        __syncthreads();
        for (int off = 1; off < KC; off <<= 1) {
            unsigned u = sb[tid];
            unsigned a = (tid >= off) ? sb[tid - off] : 0u;
            __syncthreads();
            sb[tid] = u + a;
            __syncthreads();
        }
        tstart[tid] = sb[tid] - hv;
        __syncthreads();

#pragma unroll
        for (int j = 0; j < EPT; ++j)
            if (k_r[j] != 0xFFFFFFFFu) {
                unsigned slot = tstart[k_r[j]] + rk_r[j];
                srec[slot] = make_uint2(w0_r[j], pk_r[j]);
                skey[slot] = (unsigned char)k_r[j];
            }
        __syncthreads();

        for (int i = tid; i < tn; i += 256) {
            uint2 u = srec[i];
            unsigned k = skey[i];
            unsigned pos = cursor[k] + ((unsigned)i - tstart[k]);
            w0coef[pos] = u;
        }
        __syncthreads();
        cursor[tid] += h[tid];
        __syncthreads();
    }
}

// partial degree per bucket slice: grid (K, MD); gea = bf16 in record .y low half
__global__ __launch_bounds__(256)
void pdeg_kernel(const uint2* __restrict__ w0coef, const unsigned* __restrict__ bb,
                 float* __restrict__ pdeg, int Npad) {
    __shared__ float degl[SBUCKET];
    int k = blockIdx.x, m = blockIdx.y, tid = threadIdx.x;
    for (int i = tid; i < SBUCKET; i += 256) degl[i] = 0.0f;
    unsigned lo = bb[k], hi = bb[k + 1];
    unsigned cnt = hi - lo;
    unsigned slice = (cnt + MD - 1) / MD;
    unsigned slo = lo + m * slice;
    unsigned shi = min(slo + slice, hi);
    __syncthreads();
    unsigned i0 = slo + tid;
    uint2 c0 = make_uint2(0u, 0u), c1 = make_uint2(0u, 0u);
    bool v0 = i0 < shi, v1 = i0 + 256 < shi;
    if (v0) c0 = w0coef[i0];
    if (v1) c1 = w0coef[i0 + 256];
    while (v0) {
        unsigned ni = i0 + 512;
        uint2 n0 = make_uint2(0u, 0u), n1 = make_uint2(0u, 0u);
        bool nv0 = ni < shi, nv1 = ni + 256 < shi;
        if (nv0) n0 = w0coef[ni];
        if (nv1) n1 = w0coef[ni + 256];
        atomicAdd(&degl[c0.x >> 17], __uint_as_float(c0.y << 16));
        if (v1) atomicAdd(&degl[c1.x >> 17], __uint_as_float(c1.y << 16));
        v0 = nv0; v1 = nv1; c0 = n0; c1 = n1; i0 = ni;
    }
    __syncthreads();
    for (int i = tid; i < SBUCKET; i += 256)
        pdeg[(size_t)m * Npad + ((size_t)k << S_LOG) + i] = degl[i];
}

// reduce pdeg partials -> invd2g[Npad] = 1/deg^2
__global__ void invd2_kernel(const float* __restrict__ pdeg,
                             float* __restrict__ invd2g, int Npad) {
    int n = blockIdx.x * 256 + threadIdx.x;
    if (n < Npad) {
        float d = 0.0f;
#pragma unroll
        for (int m = 0; m < MD; ++m) d += pdeg[(size_t)m * Npad + n];
        invd2g[n] = 1.0f / (d * d);
    }
}

// main accumulation: grid (K, MA) — ALL 8 batches per record in one pass.
// yT bf16x8: 1 uint4 gather per record; y0 via one ds_read_b128.
__global__ __launch_bounds__(256)
void accum_kernel(const uint2* __restrict__ w0coef, const unsigned* __restrict__ bb,
                  const float* __restrict__ invd2g, const uint4* __restrict__ yT,
                  float* __restrict__ pout, int N, int Npad) {
    __shared__ float invd2[SBUCKET];          // 2 KB
    __shared__ uint4 y0l[SBUCKET];            // 8 KB (bf16x8 per node)
    __shared__ float outl[BATCH][SBUCKET];    // 16 KB
    int k = blockIdx.x, m = blockIdx.y, tid = threadIdx.x;
    int n0 = k << S_LOG;

    for (int i = tid; i < SBUCKET; i += 256) invd2[i] = invd2g[n0 + i];
    for (int i = tid; i < BATCH * SBUCKET; i += 256) ((float*)outl)[i] = 0.0f;
    for (int j = tid; j < SBUCKET; j += 256) y0l[j] = yT[n0 + j];  // yT padded to Npad
    unsigned lo = bb[k], hi = bb[k + 1];
    unsigned cnt = hi - lo;
    unsigned slice = (cnt + MA - 1) / MA;
    unsigned slo = lo + m * slice;
    unsigned shi = min(slo + slice, hi);
    __syncthreads();

    unsigned i0 = slo + tid;
    uint2 c0 = make_uint2(0u, 0u), c1 = c0, d0 = c0, d1 = c0;
    uint4 zg = make_uint4(0u, 0u, 0u, 0u);
    uint4 g0 = zg, g1 = zg;
    bool vc0 = i0 < shi,       vc1 = i0 + 256 < shi;
    bool vd0 = i0 + 512 < shi, vd1 = i0 + 768 < shi;
    if (vc0) c0 = w0coef[i0];
    if (vc1) c1 = w0coef[i0 + 256];
    if (vd0) d0 = w0coef[i0 + 512];
    if (vd1) d1 = w0coef[i0 + 768];
    if (vc0) g0 = yT[c0.x & 0x1FFFFu];
    if (vc1) g1 = yT[c1.x & 0x1FFFFu];

    while (vc0) {
        // gathers for d-records (used next iter)
        uint4 h0 = zg, h1 = zg;
        if (vd0) h0 = yT[d0.x & 0x1FFFFu];
        if (vd1) h1 = yT[d1.x & 0x1FFFFu];
        // records 2 iters ahead
        uint2 e0 = make_uint2(0u, 0u), e1 = make_uint2(0u, 0u);
        bool ve0 = i0 + 1024 < shi, ve1 = i0 + 1280 < shi;
        if (ve0) e0 = w0coef[i0 + 1024];
        if (ve1) e1 = w0coef[i0 + 1280];

        {
            unsigned s0l = c0.x >> 17;
            float c = __uint_as_float(c0.y & 0xFFFF0000u) * invd2[s0l];
            uint4 y0r = y0l[s0l];
            const unsigned yw[4] = {y0r.x, y0r.y, y0r.z, y0r.w};
            const unsigned gw[4] = {g0.x, g0.y, g0.z, g0.w};
#pragma unroll
            for (int p = 0; p < 4; ++p) {
                float ya = __uint_as_float(yw[p] << 16);
                float yb = __uint_as_float(yw[p] & 0xFFFF0000u);
                float ga = __uint_as_float(gw[p] << 16);
                float gb = __uint_as_float(gw[p] & 0xFFFF0000u);
                float qa = c * fmaxf(ya - ga, 0.0f);
                float qb = c * fmaxf(yb - gb, 0.0f);
                if (qa != 0.0f) atomicAdd(&outl[2 * p][s0l], qa);
                if (qb != 0.0f) atomicAdd(&outl[2 * p + 1][s0l], qb);
            }
        }
        if (vc1) {
            unsigned s0l = c1.x >> 17;
            float c = __uint_as_float(c1.y & 0xFFFF0000u) * invd2[s0l];
            uint4 y0r = y0l[s0l];
            const unsigned yw[4] = {y0r.x, y0r.y, y0r.z, y0r.w};
            const unsigned gw[4] = {g1.x, g1.y, g1.z, g1.w};
#pragma unroll
            for (int p = 0; p < 4; ++p) {
                float ya = __uint_as_float(yw[p] << 16);
                float yb = __uint_as_float(yw[p] & 0xFFFF0000u);
                float ga = __uint_as_float(gw[p] << 16);
                float gb = __uint_as_float(gw[p] & 0xFFFF0000u);
                float qa = c * fmaxf(ya - ga, 0.0f);
                float qb = c * fmaxf(yb - gb, 0.0f);
                if (qa != 0.0f) atomicAdd(&outl[2 * p][s0l], qa);
                if (qb != 0.0f) atomicAdd(&outl[2 * p + 1][s0l], qb);
            }
        }

        c0 = d0; c1 = d1; d0 = e0; d1 = e1;
        g0 = h0; g1 = h1;
        vc0 = vd0; vc1 = vd1; vd0 = ve0; vd1 = ve1;
        i0 += 512;
    }
    __syncthreads();

    for (int i = tid; i < BATCH * SBUCKET; i += 256) {
        int b = i >> S_LOG;
        int j = i & (SBUCKET - 1);
        pout[((size_t)m * BATCH + b) * Npad + n0 + j] = outl[b][j];
    }
}

// out = 1 - sum_m pout : grid ((N+255)/256, BATCH)
__global__ void finalize_kernel(const float* __restrict__ pout,
                                float* __restrict__ out, int N, int Npad) {
    int n = blockIdx.x * blockDim.x + threadIdx.x;
    int b = blockIdx.y;
    if (n < N) {
        float s = 0.0f;
#pragma unroll
        for (int m = 0; m < MA; ++m)
            s += pout[((size_t)m * BATCH + b) * Npad + n];
        out[(size_t)b * N + n] = 1.0f - s;
    }
}

// ---------------- fallback (R1 path) ----------------

__global__ void fill_one_kernel(float* __restrict__ out, int n) {
    int i = blockIdx.x * blockDim.x + threadIdx.x;
    if (i < n) out[i] = 1.0f;
}

__global__ void deg_kernel(const float* __restrict__ gea,
                           const int* __restrict__ ei0,
                           float* __restrict__ deg, int E) {
    int e = blockIdx.x * blockDim.x + threadIdx.x;
    if (e < E) atomicAdd(&deg[ei0[e]], gea[e]);
}

__global__ void edge_kernel(const float* __restrict__ y,
                            const float* __restrict__ dw,
                            const int* __restrict__ ei0,
                            const int* __restrict__ ei1,
                            const float* __restrict__ deg,
                            float* __restrict__ out,
                            int E, int N) {
    int e = blockIdx.x * blockDim.x + threadIdx.x;
    if (e >= E) return;
    int s0 = ei0[e];
    int s1 = ei1[e];
    float d = deg[s0];
    float inv = 1.0f / (d * d);
    float sig = 1.0f / (1.0f + __expf(-dw[e]));
    float coef = sqrtf(sig) * inv;
#pragma unroll
    for (int b = 0; b < BATCH; ++b) {
        float y0 = y[(size_t)b * N + s0];
        float y1 = y[(size_t)b * N + s1];
        float gm = coef * fmaxf(y0 - y1, 0.0f);
        if (gm != 0.0f) atomicAdd(&out[(size_t)b * N + s0], -gm);
    }
}

// ---------------- launch ----------------

extern "C" void kernel_launch(void* const* d_in, const int* in_sizes, int n_in,
                              void* d_out, int out_size, void* d_ws, size_t ws_size,
                              hipStream_t stream) {
    const float* y   = (const float*)d_in[0];   // [B,N]
    const float* gea = (const float*)d_in[2];   // [E]
    const float* dw  = (const float*)d_in[3];   // [E]
    const int*   ei  = (const int*)d_in[4];     // [2,E]

    const int E = in_sizes[2];
    const int N = in_sizes[0] / BATCH;
    const int* ei0 = ei;
    const int* ei1 = ei + E;

    const int K = (N + SBUCKET - 1) >> S_LOG;
    const int Npad = K << S_LOG;

    size_t o_yT     = 0;
    size_t o_rcf    = o_yT     + alignup((size_t)Npad * 16);
    size_t o_counts = o_rcf    + alignup((size_t)E * 8);
    size_t o_base   = o_counts + alignup((size_t)KC * CB * 4);
    size_t o_tot    = o_base   + alignup((size_t)KC * CB * 4);
    size_t o_bb     = o_tot    + alignup((size_t)KC * 4);
    size_t o_pdeg   = o_bb     + alignup((size_t)(KC + 1) * 4);
    size_t o_inv    = o_pdeg   + alignup((size_t)MD * Npad * 4);
    size_t o_pout   = o_inv    + alignup((size_t)Npad * 4);
    size_t need     = o_pout   + alignup((size_t)MA * BATCH * Npad * 4);

    if (K <= KC && N <= 131071 && ws_size >= need) {
        char* w = (char*)d_ws;
        uint4*    yT     = (uint4*)(w + o_yT);
        uint2*    w0coef = (uint2*)(w + o_rcf);
        unsigned* counts = (unsigned*)(w + o_counts);
        unsigned* base   = (unsigned*)(w + o_base);
        unsigned* tot    = (unsigned*)(w + o_tot);
        unsigned* bb     = (unsigned*)(w + o_bb);
        float*    pdeg   = (float*)(w + o_pdeg);
        float*    invd2g = (float*)(w + o_inv);
        float*    pout   = (float*)(w + o_pout);

        int tb = (Npad + 255) / 256;
        count_transpose_kernel<<<CB + tb, 256, 0, stream>>>(ei0, counts, y, yT,
                                                            E, N, Npad);
        scanB1_kernel<<<K, 256, 0, stream>>>(counts, base, tot);
        scanC_kernel<<<1, KC, 0, stream>>>(tot, bb, E, K);
        scatter_kernel<<<CB, 256, 0, stream>>>(ei0, ei1, dw, gea, base, bb,
                                               w0coef, E);
        pdeg_kernel<<<dim3(K, MD), 256, 0, stream>>>(w0coef, bb, pdeg, Npad);
        invd2_kernel<<<(Npad + 255) / 256, 256, 0, stream>>>(pdeg, invd2g, Npad);
        accum_kernel<<<dim3(K, MA), 256, 0, stream>>>(w0coef, bb, invd2g, yT,
                                                      pout, N, Npad);
        finalize_kernel<<<dim3((N + 255) / 256, BATCH), 256, 0, stream>>>(
            pout, (float*)d_out, N, Npad);
    } else {
        float* deg = (float*)d_ws;
        hipMemsetAsync(deg, 0, (size_t)N * sizeof(float), stream);
        fill_one_kernel<<<(out_size + 255) / 256, 256, 0, stream>>>((float*)d_out, out_size);
        deg_kernel<<<(E + 255) / 256, 256, 0, stream>>>(gea, ei0, deg, E);
        edge_kernel<<<(E + 255) / 256, 256, 0, stream>>>(y, dw, ei0, ei1, deg,
                                                         (float*)d_out, E, N);
    }
}

// Round 11
// 239.128 us; speedup vs baseline: 1.1941x; 1.0200x over previous
//
#include <hip/hip_runtime.h>

#define BATCH 8
#define S_LOG 9
#define SBUCKET 512          // nodes per bucket
#define KC 256               // max buckets (N <= 131071)
#define CB 1024              // blocks for count/scatter
#define TTILE 2048           // edges per sort tile
#define EPT (TTILE / 256)    // edges per thread per tile
#define MA 8                 // accum sub-blocks per bucket

static inline size_t alignup(size_t x) { return (x + 255) & ~(size_t)255; }

__device__ __forceinline__ unsigned bf16hi(unsigned u) {
    // fp32 -> bf16 (rne), returned in LOW 16 bits
    return (u + 0x7FFFu + ((u >> 16) & 1u)) >> 16;
}

// ---------------- pipeline kernels ----------------

// fused: blocks [0,CB) bucket-count; blocks [CB,...) transpose y -> yT[node] = 8 bf16 (uint4)
__global__ __launch_bounds__(256)
void count_transpose_kernel(const int* __restrict__ ei0, unsigned* __restrict__ counts,
                            const float* __restrict__ y, uint4* __restrict__ yT,
                            int E, int N, int Npad) {
    __shared__ unsigned cnt[KC];
    int tid = threadIdx.x;
    if (blockIdx.x >= CB) {
        int n = (blockIdx.x - CB) * 256 + tid;
        if (n < Npad) {
            uint4 o = make_uint4(0u, 0u, 0u, 0u);
            if (n < N) {
                unsigned p[8];
#pragma unroll
                for (int b = 0; b < BATCH; ++b)
                    p[b] = bf16hi(__float_as_uint(y[(size_t)b * N + n]));
                o = make_uint4(p[0] | (p[1] << 16), p[2] | (p[3] << 16),
                               p[4] | (p[5] << 16), p[6] | (p[7] << 16));
            }
            yT[n] = o;
        }
        return;
    }
    cnt[tid] = 0;
    __syncthreads();
    int chunk = (E + CB - 1) / CB;
    int lo = blockIdx.x * chunk;
    int hi = min(lo + chunk, E);
    for (int i = lo + tid; i < hi; i += 256)
        atomicAdd(&cnt[ei0[i] >> S_LOG], 1u);
    __syncthreads();
    counts[(size_t)tid * CB + blockIdx.x] = cnt[tid];   // [bucket][block]
}

// scanB1: one block per bucket — local exclusive prefix of counts[k][0..CB) -> base,
// and bucket total -> tot[k]. Fully coalesced uint4 loads/stores.
__global__ __launch_bounds__(256)
void scanB1_kernel(const unsigned* __restrict__ counts, unsigned* __restrict__ base,
                   unsigned* __restrict__ tot) {
    __shared__ unsigned ssum[256];
    int k = blockIdx.x, tid = threadIdx.x;
    const uint4* row4 = (const uint4*)(counts + (size_t)k * CB);
    uint4 v = row4[tid];
    unsigned lsum = v.x + v.y + v.z + v.w;
    ssum[tid] = lsum;
    __syncthreads();
    for (int off = 1; off < 256; off <<= 1) {
        unsigned u = ssum[tid];
        unsigned a = (tid >= off) ? ssum[tid - off] : 0u;
        __syncthreads();
        ssum[tid] = u + a;
        __syncthreads();
    }
    unsigned ex = ssum[tid] - lsum;
    if (tid == 255) tot[k] = ssum[255];
    uint4 o;
    o.x = ex;
    o.y = ex + v.x;
    o.z = o.y + v.y;
    o.w = o.z + v.z;
    ((uint4*)(base + (size_t)k * CB))[tid] = o;
}

// scanC: one block — exclusive scan of bucket totals -> bb[0..KC], bb[KC]=E
__global__ void scanC_kernel(const unsigned* __restrict__ tot,
                             unsigned* __restrict__ bb, int E, int K) {
    __shared__ unsigned sb[KC];
    int t = threadIdx.x;
    unsigned v = (t < K) ? tot[t] : 0u;
    sb[t] = v;
    __syncthreads();
    for (int off = 1; off < KC; off <<= 1) {
        unsigned u = sb[t];
        unsigned a = (t >= off) ? sb[t - off] : 0u;
        __syncthreads();
        sb[t] = u + a;
        __syncthreads();
    }
    bb[t] = sb[t] - v;
    if (t == KC - 1) bb[KC] = (unsigned)E;
}

// scatter: bucket-sort edges into w0coef records.
// record: .x = s1 | s0l<<17 ; .y = bf16(coef)<<16 | bf16(gea)
// wave-shuffle scans: ~6 barriers per tile instead of ~20.
__global__ __launch_bounds__(256)
void scatter_kernel(const int* __restrict__ ei0, const int* __restrict__ ei1,
                    const float* __restrict__ dw, const float* __restrict__ gea,
                    const unsigned* __restrict__ base, const unsigned* __restrict__ bb,
                    uint2* __restrict__ w0coef, int E) {
    __shared__ unsigned cursor[KC];
    __shared__ unsigned h[KC];
    __shared__ unsigned tstart[KC];
    __shared__ unsigned wsum[4];
    __shared__ uint2 srec[TTILE];            // 16 KB
    __shared__ unsigned char skey[TTILE];    // 2 KB
    int tid = threadIdx.x;
    cursor[tid] = base[(size_t)tid * CB + blockIdx.x] + bb[tid];
    int chunk = (E + CB - 1) / CB;
    int lo = blockIdx.x * chunk;
    int hi = min(lo + chunk, E);
    __syncthreads();

    for (int tileLo = lo; tileLo < hi; tileLo += TTILE) {
        int tn = min(TTILE, hi - tileLo);
        h[tid] = 0;
        __syncthreads();

        unsigned k_r[EPT], w0_r[EPT], pk_r[EPT], rk_r[EPT];
#pragma unroll
        for (int j = 0; j < EPT; ++j) {
            int off = j * 256 + tid;
            k_r[j] = 0xFFFFFFFFu;
            if (off < tn) {
                int i = tileLo + off;
                int s0v = ei0[i];
                int s1v = ei1[i];
                unsigned k = (unsigned)s0v >> S_LOG;
                unsigned s0l = (unsigned)(s0v & (SBUCKET - 1));
                k_r[j] = k;
                w0_r[j] = (unsigned)s1v | (s0l << 17);
                float sig = 1.0f / (1.0f + __expf(-dw[i]));
                unsigned cf = __float_as_uint(sqrtf(sig));
                unsigned gu = __float_as_uint(gea[i]);
                pk_r[j] = (bf16hi(cf) << 16) | bf16hi(gu);
            }
        }
#pragma unroll
        for (int j = 0; j < EPT; ++j)
            if (k_r[j] != 0xFFFFFFFFu) rk_r[j] = atomicAdd(&h[k_r[j]], 1u);
        __syncthreads();

        // exclusive scan of h[256] via wave shuffles (1 barrier)
        unsigned hv = h[tid];
        unsigned v = hv;
        unsigned lane = tid & 63;
        unsigned wv = tid >> 6;
#pragma unroll
        for (int off = 1; off < 64; off <<= 1) {
            unsigned t = __shfl_up(v, off, 64);
            if (lane >= off) v += t;
        }
        if (lane == 63) wsum[wv] = v;
        __syncthreads();
        unsigned addv = 0;
#pragma unroll
        for (unsigned w = 0; w < 4; ++w)
            if (w < wv) addv += wsum[w];
        tstart[tid] = v + addv - hv;
        __syncthreads();

#pragma unroll
        for (int j = 0; j < EPT; ++j)
            if (k_r[j] != 0xFFFFFFFFu) {
                unsigned slot = tstart[k_r[j]] + rk_r[j];
                srec[slot] = make_uint2(w0_r[j], pk_r[j]);
                skey[slot] = (unsigned char)k_r[j];
            }
        __syncthreads();

        for (int i = tid; i < tn; i += 256) {
            uint2 u = srec[i];
            unsigned k = skey[i];
            unsigned pos = cursor[k] + ((unsigned)i - tstart[k]);
            w0coef[pos] = u;
        }
        __syncthreads();
        cursor[tid] += h[tid];
        __syncthreads();
    }
}

// main accumulation: grid (K, MA) — all 8 batches + partial deg per record.
// outl holds UNSCALED sum of coef*max(y0-y1); invd2 applied in finalize.
__global__ __launch_bounds__(256)
void accum_kernel(const uint2* __restrict__ w0coef, const unsigned* __restrict__ bb,
                  const uint4* __restrict__ yT,
                  float* __restrict__ pdegp, float* __restrict__ pout,
                  int N, int Npad) {
    __shared__ float degl[SBUCKET];               // 2 KB
    __shared__ uint4 y0l[SBUCKET];                // 8 KB
    __shared__ float outl[BATCH][SBUCKET + 1];    // 16 KB (padded rows)
    int k = blockIdx.x, m = blockIdx.y, tid = threadIdx.x;
    int n0 = k << S_LOG;

    for (int i = tid; i < SBUCKET; i += 256) degl[i] = 0.0f;
    for (int i = tid; i < BATCH * (SBUCKET + 1); i += 256) ((float*)outl)[i] = 0.0f;
    for (int j = tid; j < SBUCKET; j += 256) y0l[j] = yT[n0 + j];   // yT padded
    unsigned lo = bb[k], hi = bb[k + 1];
    unsigned cnt = hi - lo;
    unsigned slice = (cnt + MA - 1) / MA;
    unsigned slo = lo + m * slice;
    unsigned shi = min(slo + slice, hi);
    __syncthreads();

    unsigned i0 = slo + tid;
    uint2 z2 = make_uint2(0u, 0u);
    uint2 c0 = z2, c1 = z2, d0 = z2, d1 = z2, e0 = z2, e1 = z2;
    uint4 zg = make_uint4(0u, 0u, 0u, 0u);
    uint4 g0 = zg, g1 = zg, h0 = zg, h1 = zg;
    bool vc0 = i0 < shi,        vc1 = i0 + 256 < shi;
    bool vd0 = i0 + 512 < shi,  vd1 = i0 + 768 < shi;
    bool ve0 = i0 + 1024 < shi, ve1 = i0 + 1280 < shi;
    if (vc0) c0 = w0coef[i0];
    if (vc1) c1 = w0coef[i0 + 256];
    if (vd0) d0 = w0coef[i0 + 512];
    if (vd1) d1 = w0coef[i0 + 768];
    if (ve0) e0 = w0coef[i0 + 1024];
    if (ve1) e1 = w0coef[i0 + 1280];
    if (vc0) g0 = yT[c0.x & 0x1FFFFu];
    if (vc1) g1 = yT[c1.x & 0x1FFFFu];
    if (vd0) h0 = yT[d0.x & 0x1FFFFu];
    if (vd1) h1 = yT[d1.x & 0x1FFFFu];

    while (vc0) {
        // gathers for e-records (used 2 iters from now)
        uint4 p0 = zg, p1 = zg;
        if (ve0) p0 = yT[e0.x & 0x1FFFFu];
        if (ve1) p1 = yT[e1.x & 0x1FFFFu];
        // records 3 iters ahead
        uint2 f0 = z2, f1 = z2;
        bool vf0 = i0 + 1536 < shi, vf1 = i0 + 1792 < shi;
        if (vf0) f0 = w0coef[i0 + 1536];
        if (vf1) f1 = w0coef[i0 + 1792];

        {
            unsigned s0l = c0.x >> 17;
            float cf = __uint_as_float(c0.y & 0xFFFF0000u);
            atomicAdd(&degl[s0l], __uint_as_float(c0.y << 16));
            uint4 y0r = y0l[s0l];
            const unsigned yw[4] = {y0r.x, y0r.y, y0r.z, y0r.w};
            const unsigned gw[4] = {g0.x, g0.y, g0.z, g0.w};
#pragma unroll
            for (int p = 0; p < 4; ++p) {
                float ya = __uint_as_float(yw[p] << 16);
                float yb = __uint_as_float(yw[p] & 0xFFFF0000u);
                float ga = __uint_as_float(gw[p] << 16);
                float gb = __uint_as_float(gw[p] & 0xFFFF0000u);
                float qa = cf * fmaxf(ya - ga, 0.0f);
                float qb = cf * fmaxf(yb - gb, 0.0f);
                if (qa != 0.0f) atomicAdd(&outl[2 * p][s0l], qa);
                if (qb != 0.0f) atomicAdd(&outl[2 * p + 1][s0l], qb);
            }
        }
        if (vc1) {
            unsigned s0l = c1.x >> 17;
            float cf = __uint_as_float(c1.y & 0xFFFF0000u);
            atomicAdd(&degl[s0l], __uint_as_float(c1.y << 16));
            uint4 y0r = y0l[s0l];
            const unsigned yw[4] = {y0r.x, y0r.y, y0r.z, y0r.w};
            const unsigned gw[4] = {g1.x, g1.y, g1.z, g1.w};
#pragma unroll
            for (int p = 0; p < 4; ++p) {
                float ya = __uint_as_float(yw[p] << 16);
                float yb = __uint_as_float(yw[p] & 0xFFFF0000u);
                float ga = __uint_as_float(gw[p] << 16);
                float gb = __uint_as_float(gw[p] & 0xFFFF0000u);
                float qa = cf * fmaxf(ya - ga, 0.0f);
                float qb = cf * fmaxf(yb - gb, 0.0f);
                if (qa != 0.0f) atomicAdd(&outl[2 * p][s0l], qa);
                if (qb != 0.0f) atomicAdd(&outl[2 * p + 1][s0l], qb);
            }
        }

        c0 = d0; c1 = d1; d0 = e0; d1 = e1; e0 = f0; e1 = f1;
        g0 = h0; g1 = h1; h0 = p0; h1 = p1;
        vc0 = vd0; vc1 = vd1; vd0 = ve0; vd1 = ve1; ve0 = vf0; ve1 = vf1;
        i0 += 512;
    }
    __syncthreads();

    for (int i = tid; i < SBUCKET; i += 256)
        pdegp[(size_t)m * Npad + n0 + i] = degl[i];
    for (int i = tid; i < BATCH * SBUCKET; i += 256) {
        int b = i >> S_LOG;
        int j = i & (SBUCKET - 1);
        pout[((size_t)m * BATCH + b) * Npad + n0 + j] = outl[b][j];
    }
}

// out[b*N+n] = 1 - (sum_m pout) / deg^2, deg = sum_m pdegp. One thread per node.
__global__ __launch_bounds__(256)
void finalize_kernel(const float* __restrict__ pdegp, const float* __restrict__ pout,
                     float* __restrict__ out, int N, int Npad) {
    int n = blockIdx.x * blockDim.x + threadIdx.x;
    if (n >= N) return;
    float d = 0.0f;
#pragma unroll
    for (int m = 0; m < MA; ++m) d += pdegp[(size_t)m * Npad + n];
    float inv = 1.0f / (d * d);
#pragma unroll
    for (int b = 0; b < BATCH; ++b) {
        float s = 0.0f;
#pragma unroll
        for (int m = 0; m < MA; ++m)
            s += pout[((size_t)m * BATCH + b) * Npad + n];
        out[(size_t)b * N + n] = 1.0f - s * inv;
    }
}

// ---------------- fallback (R1 path) ----------------

__global__ void fill_one_kernel(float* __restrict__ out, int n) {
    int i = blockIdx.x * blockDim.x + threadIdx.x;
    if (i < n) out[i] = 1.0f;
}

__global__ void deg_kernel(const float* __restrict__ gea,
                           const int* __restrict__ ei0,
                           float* __restrict__ deg, int E) {
    int e = blockIdx.x * blockDim.x + threadIdx.x;
    if (e < E) atomicAdd(&deg[ei0[e]], gea[e]);
}

__global__ void edge_kernel(const float* __restrict__ y,
                            const float* __restrict__ dw,
                            const int* __restrict__ ei0,
                            const int* __restrict__ ei1,
                            const float* __restrict__ deg,
                            float* __restrict__ out,
                            int E, int N) {
    int e = blockIdx.x * blockDim.x + threadIdx.x;
    if (e >= E) return;
    int s0 = ei0[e];
    int s1 = ei1[e];
    float d = deg[s0];
    float inv = 1.0f / (d * d);
    float sig = 1.0f / (1.0f + __expf(-dw[e]));
    float coef = sqrtf(sig) * inv;
#pragma unroll
    for (int b = 0; b < BATCH; ++b) {
        float y0 = y[(size_t)b * N + s0];
        float y1 = y[(size_t)b * N + s1];
        float gm = coef * fmaxf(y0 - y1, 0.0f);
        if (gm != 0.0f) atomicAdd(&out[(size_t)b * N + s0], -gm);
    }
}

// ---------------- launch ----------------

extern "C" void kernel_launch(void* const* d_in, const int* in_sizes, int n_in,
                              void* d_out, int out_size, void* d_ws, size_t ws_size,
                              hipStream_t stream) {
    const float* y   = (const float*)d_in[0];   // [B,N]
    const float* gea = (const float*)d_in[2];   // [E]
    const float* dw  = (const float*)d_in[3];   // [E]
    const int*   ei  = (const int*)d_in[4];     // [2,E]

    const int E = in_sizes[2];
    const int N = in_sizes[0] / BATCH;
    const int* ei0 = ei;
    const int* ei1 = ei + E;

    const int K = (N + SBUCKET - 1) >> S_LOG;
    const int Npad = K << S_LOG;

    size_t o_yT     = 0;
    size_t o_rcf    = o_yT     + alignup((size_t)Npad * 16);
    size_t o_counts = o_rcf    + alignup((size_t)E * 8);
    size_t o_base   = o_counts + alignup((size_t)KC * CB * 4);
    size_t o_tot    = o_base   + alignup((size_t)KC * CB * 4);
    size_t o_bb     = o_tot    + alignup((size_t)KC * 4);
    size_t o_pdegp  = o_bb     + alignup((size_t)(KC + 1) * 4);
    size_t o_pout   = o_pdegp  + alignup((size_t)MA * Npad * 4);
    size_t need     = o_pout   + alignup((size_t)MA * BATCH * Npad * 4);

    if (K <= KC && N <= 131071 && ws_size >= need) {
        char* w = (char*)d_ws;
        uint4*    yT     = (uint4*)(w + o_yT);
        uint2*    w0coef = (uint2*)(w + o_rcf);
        unsigned* counts = (unsigned*)(w + o_counts);
        unsigned* base   = (unsigned*)(w + o_base);
        unsigned* tot    = (unsigned*)(w + o_tot);
        unsigned* bb     = (unsigned*)(w + o_bb);
        float*    pdegp  = (float*)(w + o_pdegp);
        float*    pout   = (float*)(w + o_pout);

        int tb = (Npad + 255) / 256;
        count_transpose_kernel<<<CB + tb, 256, 0, stream>>>(ei0, counts, y, yT,
                                                            E, N, Npad);
        scanB1_kernel<<<K, 256, 0, stream>>>(counts, base, tot);
        scanC_kernel<<<1, KC, 0, stream>>>(tot, bb, E, K);
        scatter_kernel<<<CB, 256, 0, stream>>>(ei0, ei1, dw, gea, base, bb,
                                               w0coef, E);
        accum_kernel<<<dim3(K, MA), 256, 0, stream>>>(w0coef, bb, yT,
                                                      pdegp, pout, N, Npad);
        finalize_kernel<<<(N + 255) / 256, 256, 0, stream>>>(
            pdegp, pout, (float*)d_out, N, Npad);
    } else {
        float* deg = (float*)d_ws;
        (void)hipMemsetAsync(deg, 0, (size_t)N * sizeof(float), stream);
        fill_one_kernel<<<(out_size + 255) / 256, 256, 0, stream>>>((float*)d_out, out_size);
        deg_kernel<<<(E + 255) / 256, 256, 0, stream>>>(gea, ei0, deg, E);
        edge_kernel<<<(E + 255) / 256, 256, 0, stream>>>(y, dw, ei0, ei1, deg,
                                                         (float*)d_out, E, N);
    }
}

// Round 13
// 177.291 us; speedup vs baseline: 1.6106x; 1.3488x over previous
//
#include <hip/hip_runtime.h>
#include <hip/hip_fp16.h>

#define BATCH 8
#define S_LOG 9
#define SBUCKET 512          // nodes per bucket
#define KC 256               // max buckets (N <= 131071)
#define CB 1024              // blocks for count/scatter
#define TTILE 2048           // edges per sort tile
#define EPT (TTILE / 256)    // edges per thread per tile
#define MA 8                 // accum sub-blocks per bucket

static inline size_t alignup(size_t x) { return (x + 255) & ~(size_t)255; }

__device__ __forceinline__ unsigned bf16hi(unsigned u) {
    // fp32 -> bf16 (rne), returned in LOW 16 bits
    return (u + 0x7FFFu + ((u >> 16) & 1u)) >> 16;
}

// ---------------- pipeline kernels ----------------

// fused: blocks [0,CB) bucket-count; blocks [CB,...) transpose y -> yT[node] = 8 bf16 (uint4)
__global__ __launch_bounds__(256)
void count_transpose_kernel(const int* __restrict__ ei0, unsigned* __restrict__ counts,
                            const float* __restrict__ y, uint4* __restrict__ yT,
                            int E, int N, int Npad) {
    __shared__ unsigned cnt[KC];
    int tid = threadIdx.x;
    if (blockIdx.x >= CB) {
        int n = (blockIdx.x - CB) * 256 + tid;
        if (n < Npad) {
            uint4 o = make_uint4(0u, 0u, 0u, 0u);
            if (n < N) {
                unsigned p[8];
#pragma unroll
                for (int b = 0; b < BATCH; ++b)
                    p[b] = bf16hi(__float_as_uint(y[(size_t)b * N + n]));
                o = make_uint4(p[0] | (p[1] << 16), p[2] | (p[3] << 16),
                               p[4] | (p[5] << 16), p[6] | (p[7] << 16));
            }
            yT[n] = o;
        }
        return;
    }
    cnt[tid] = 0;
    __syncthreads();
    int chunk = (E + CB - 1) / CB;
    int lo = blockIdx.x * chunk;
    int hi = min(lo + chunk, E);
    for (int i = lo + tid; i < hi; i += 256)
        atomicAdd(&cnt[ei0[i] >> S_LOG], 1u);
    __syncthreads();
    counts[(size_t)tid * CB + blockIdx.x] = cnt[tid];   // [bucket][block]
}

// scanB1: one block per bucket — local exclusive prefix of counts[k][0..CB) -> base,
// and bucket total -> tot[k].
__global__ __launch_bounds__(256)
void scanB1_kernel(const unsigned* __restrict__ counts, unsigned* __restrict__ base,
                   unsigned* __restrict__ tot) {
    __shared__ unsigned ssum[256];
    int k = blockIdx.x, tid = threadIdx.x;
    const uint4* row4 = (const uint4*)(counts + (size_t)k * CB);
    uint4 v = row4[tid];
    unsigned lsum = v.x + v.y + v.z + v.w;
    ssum[tid] = lsum;
    __syncthreads();
    for (int off = 1; off < 256; off <<= 1) {
        unsigned u = ssum[tid];
        unsigned a = (tid >= off) ? ssum[tid - off] : 0u;
        __syncthreads();
        ssum[tid] = u + a;
        __syncthreads();
    }
    unsigned ex = ssum[tid] - lsum;
    if (tid == 255) tot[k] = ssum[255];
    uint4 o;
    o.x = ex;
    o.y = ex + v.x;
    o.z = o.y + v.y;
    o.w = o.z + v.z;
    ((uint4*)(base + (size_t)k * CB))[tid] = o;
}

// scanC: one block — exclusive scan of bucket totals -> bb[0..KC], bb[KC]=E
__global__ void scanC_kernel(const unsigned* __restrict__ tot,
                             unsigned* __restrict__ bb, int E, int K) {
    __shared__ unsigned sb[KC];
    int t = threadIdx.x;
    unsigned v = (t < K) ? tot[t] : 0u;
    sb[t] = v;
    __syncthreads();
    for (int off = 1; off < KC; off <<= 1) {
        unsigned u = sb[t];
        unsigned a = (t >= off) ? sb[t - off] : 0u;
        __syncthreads();
        sb[t] = u + a;
        __syncthreads();
    }
    bb[t] = sb[t] - v;
    if (t == KC - 1) bb[KC] = (unsigned)E;
}

// scatter: bucket-sort edges into w0coef records.
// record: .x = s1 | s0l<<17 ; .y = bf16(coef)<<16 | bf16(gea)
__global__ __launch_bounds__(256)
void scatter_kernel(const int* __restrict__ ei0, const int* __restrict__ ei1,
                    const float* __restrict__ dw, const float* __restrict__ gea,
                    const unsigned* __restrict__ base, const unsigned* __restrict__ bb,
                    uint2* __restrict__ w0coef, int E) {
    __shared__ unsigned cursor[KC];
    __shared__ unsigned h[KC];
    __shared__ unsigned tstart[KC];
    __shared__ unsigned wsum[4];
    __shared__ uint2 srec[TTILE];            // 16 KB
    __shared__ unsigned char skey[TTILE];    // 2 KB
    int tid = threadIdx.x;
    cursor[tid] = base[(size_t)tid * CB + blockIdx.x] + bb[tid];
    int chunk = (E + CB - 1) / CB;
    int lo = blockIdx.x * chunk;
    int hi = min(lo + chunk, E);
    __syncthreads();

    for (int tileLo = lo; tileLo < hi; tileLo += TTILE) {
        int tn = min(TTILE, hi - tileLo);
        h[tid] = 0;
        __syncthreads();

        unsigned k_r[EPT], w0_r[EPT], pk_r[EPT], rk_r[EPT];
#pragma unroll
        for (int j = 0; j < EPT; ++j) {
            int off = j * 256 + tid;
            k_r[j] = 0xFFFFFFFFu;
            if (off < tn) {
                int i = tileLo + off;
                int s0v = ei0[i];
                int s1v = ei1[i];
                unsigned k = (unsigned)s0v >> S_LOG;
                unsigned s0l = (unsigned)(s0v & (SBUCKET - 1));
                k_r[j] = k;
                w0_r[j] = (unsigned)s1v | (s0l << 17);
                float sig = 1.0f / (1.0f + __expf(-dw[i]));
                unsigned cf = __float_as_uint(sqrtf(sig));
                unsigned gu = __float_as_uint(gea[i]);
                pk_r[j] = (bf16hi(cf) << 16) | bf16hi(gu);
            }
        }
#pragma unroll
        for (int j = 0; j < EPT; ++j)
            if (k_r[j] != 0xFFFFFFFFu) rk_r[j] = atomicAdd(&h[k_r[j]], 1u);
        __syncthreads();

        // exclusive scan of h[256] via wave shuffles
        unsigned hv = h[tid];
        unsigned v = hv;
        unsigned lane = tid & 63;
        unsigned wv = tid >> 6;
#pragma unroll
        for (int off = 1; off < 64; off <<= 1) {
            unsigned t = __shfl_up(v, off, 64);
            if (lane >= off) v += t;
        }
        if (lane == 63) wsum[wv] = v;
        __syncthreads();
        unsigned addv = 0;
#pragma unroll
        for (unsigned w = 0; w < 4; ++w)
            if (w < wv) addv += wsum[w];
        tstart[tid] = v + addv - hv;
        __syncthreads();

#pragma unroll
        for (int j = 0; j < EPT; ++j)
            if (k_r[j] != 0xFFFFFFFFu) {
                unsigned slot = tstart[k_r[j]] + rk_r[j];
                srec[slot] = make_uint2(w0_r[j], pk_r[j]);
                skey[slot] = (unsigned char)k_r[j];
            }
        __syncthreads();

        for (int i = tid; i < tn; i += 256) {
            uint2 u = srec[i];
            unsigned k = skey[i];
            unsigned pos = cursor[k] + ((unsigned)i - tstart[k]);
            w0coef[pos] = u;
        }
        __syncthreads();
        cursor[tid] += h[tid];
        __syncthreads();
    }
}

// main accumulation: grid (K, MA) — NO LDS atomics.
// Per-wave private accumulators (fp16 pairs for the 8 batches, fp32 for deg);
// within-window duplicate s0l resolved by 9-bit ballot grouping + rank-ordered
// plain read-modify-write rounds.
__global__ __launch_bounds__(256)
void accum_kernel(const uint2* __restrict__ w0coef, const unsigned* __restrict__ bb,
                  const uint4* __restrict__ yT,
                  float* __restrict__ pdegp, float* __restrict__ pout,
                  int N, int Npad) {
    __shared__ uint4  y0l[SBUCKET];               // 8 KB
    __shared__ __half2 outw[4][4][SBUCKET];       // 32 KB: [wave][batchpair][node]
    __shared__ float  degw[4][SBUCKET];           // 8 KB:  [wave][node]
    int k = blockIdx.x, m = blockIdx.y, tid = threadIdx.x;
    int n0 = k << S_LOG;
    unsigned lane = tid & 63;
    unsigned wv = tid >> 6;

    for (int i = tid; i < 4 * 4 * SBUCKET; i += 256)
        ((unsigned*)outw)[i] = 0u;
    for (int i = tid; i < 4 * SBUCKET; i += 256)
        ((float*)degw)[i] = 0.0f;
    for (int j = tid; j < SBUCKET; j += 256) y0l[j] = yT[n0 + j];   // yT padded
    unsigned lo = bb[k], hi = bb[k + 1];
    unsigned cnt = hi - lo;
    unsigned slice = (cnt + MA - 1) / MA;
    unsigned slo = lo + m * slice;
    unsigned shi = min(slo + slice, hi);
    __syncthreads();

    __half2 (*myout)[SBUCKET] = outw[wv];
    float* mydeg = degw[wv];

    unsigned i0 = slo + tid;
    uint2 z2 = make_uint2(0u, 0u);
    uint2 c0 = z2, c1 = z2, d0 = z2, d1 = z2;
    uint4 zg = make_uint4(0u, 0u, 0u, 0u);
    uint4 g0 = zg, g1 = zg;
    bool vc0 = i0 < shi,       vc1 = i0 + 256 < shi;
    bool vd0 = i0 + 512 < shi, vd1 = i0 + 768 < shi;
    if (vc0) c0 = w0coef[i0];
    if (vc1) c1 = w0coef[i0 + 256];
    if (vd0) d0 = w0coef[i0 + 512];
    if (vd1) d1 = w0coef[i0 + 768];
    if (vc0) g0 = yT[c0.x & 0x1FFFFu];
    if (vc1) g1 = yT[c1.x & 0x1FFFFu];

    while (__any(vc0)) {
        uint4 h0 = zg, h1 = zg;
        if (vd0) h0 = yT[d0.x & 0x1FFFFu];
        if (vd1) h1 = yT[d1.x & 0x1FFFFu];
        uint2 e0 = z2, e1 = z2;
        bool ve0 = i0 + 1024 < shi, ve1 = i0 + 1280 < shi;
        if (ve0) e0 = w0coef[i0 + 1024];
        if (ve1) e1 = w0coef[i0 + 1280];

#pragma unroll
        for (int half = 0; half < 2; ++half) {
            bool val = half ? vc1 : vc0;
            uint2 cc = half ? c1 : c0;
            uint4 gg = half ? g1 : g0;
            unsigned s0l = cc.x >> 17;
            // 9-bit ballot grouping of s0l across the wave
            unsigned long long mm = ~0ull;
#pragma unroll
            for (int b = 0; b < 9; ++b) {
                unsigned long long vb = __ballot((s0l >> b) & 1u);
                mm &= ((s0l >> b) & 1u) ? vb : ~vb;
            }
            unsigned rank = __popcll(mm & ((1ull << lane) - 1ull));
            // compute the 8 q values + gea
            float cf = __uint_as_float(cc.y & 0xFFFF0000u);
            float ge = __uint_as_float(cc.y << 16);
            uint4 y0r = y0l[s0l];
            float q[8];
            {
                const unsigned yw[4] = {y0r.x, y0r.y, y0r.z, y0r.w};
                const unsigned gw[4] = {gg.x, gg.y, gg.z, gg.w};
#pragma unroll
                for (int p = 0; p < 4; ++p) {
                    float ya = __uint_as_float(yw[p] << 16);
                    float yb = __uint_as_float(yw[p] & 0xFFFF0000u);
                    float ga = __uint_as_float(gw[p] << 16);
                    float gb = __uint_as_float(gw[p] & 0xFFFF0000u);
                    q[2 * p]     = cf * fmaxf(ya - ga, 0.0f);
                    q[2 * p + 1] = cf * fmaxf(yb - gb, 0.0f);
                }
            }
            // rank-ordered plain RMW rounds (no atomics)
            unsigned r = 0;
            bool pending = val;
            while (__any(pending && rank >= r ? 1 : 0)) {
                if (pending && rank == r) {
#pragma unroll
                    for (int p = 0; p < 4; ++p) {
                        float2 f = __half22float2(myout[p][s0l]);
                        f.x += q[2 * p];
                        f.y += q[2 * p + 1];
                        myout[p][s0l] = __floats2half2_rn(f.x, f.y);
                    }
                    mydeg[s0l] += ge;
                    pending = false;
                }
                ++r;
            }
        }

        c0 = d0; c1 = d1; d0 = e0; d1 = e1;
        g0 = h0; g1 = h1;
        vc0 = vd0; vc1 = vd1; vd0 = ve0; vd1 = ve1;
        i0 += 512;
    }
    __syncthreads();

    for (int i = tid; i < SBUCKET; i += 256) {
        float d = degw[0][i] + degw[1][i] + degw[2][i] + degw[3][i];
        pdegp[(size_t)m * Npad + n0 + i] = d;
    }
    for (int i = tid; i < BATCH * SBUCKET; i += 256) {
        int b = i >> S_LOG;
        int j = i & (SBUCKET - 1);
        int p = b >> 1;
        float s = 0.0f;
#pragma unroll
        for (int w = 0; w < 4; ++w) {
            float2 f = __half22float2(outw[w][p][j]);
            s += (b & 1) ? f.y : f.x;
        }
        pout[((size_t)m * BATCH + b) * Npad + n0 + j] = s;
    }
}

// out[b*N+n] = 1 - (sum_m pout) / deg^2, deg = sum_m pdegp. One thread per node.
__global__ __launch_bounds__(256)
void finalize_kernel(const float* __restrict__ pdegp, const float* __restrict__ pout,
                     float* __restrict__ out, int N, int Npad) {
    int n = blockIdx.x * blockDim.x + threadIdx.x;
    if (n >= N) return;
    float d = 0.0f;
#pragma unroll
    for (int m = 0; m < MA; ++m) d += pdegp[(size_t)m * Npad + n];
    float inv = 1.0f / (d * d);
#pragma unroll
    for (int b = 0; b < BATCH; ++b) {
        float s = 0.0f;
#pragma unroll
        for (int m = 0; m < MA; ++m)
            s += pout[((size_t)m * BATCH + b) * Npad + n];
        out[(size_t)b * N + n] = 1.0f - s * inv;
    }
}

// ---------------- fallback (R1 path) ----------------

__global__ void fill_one_kernel(float* __restrict__ out, int n) {
    int i = blockIdx.x * blockDim.x + threadIdx.x;
    if (i < n) out[i] = 1.0f;
}

__global__ void deg_kernel(const float* __restrict__ gea,
                           const int* __restrict__ ei0,
                           float* __restrict__ deg, int E) {
    int e = blockIdx.x * blockDim.x + threadIdx.x;
    if (e < E) atomicAdd(&deg[ei0[e]], gea[e]);
}

__global__ void edge_kernel(const float* __restrict__ y,
                            const float* __restrict__ dw,
                            const int* __restrict__ ei0,
                            const int* __restrict__ ei1,
                            const float* __restrict__ deg,
                            float* __restrict__ out,
                            int E, int N) {
    int e = blockIdx.x * blockDim.x + threadIdx.x;
    if (e >= E) return;
    int s0 = ei0[e];
    int s1 = ei1[e];
    float d = deg[s0];
    float inv = 1.0f / (d * d);
    float sig = 1.0f / (1.0f + __expf(-dw[e]));
    float coef = sqrtf(sig) * inv;
#pragma unroll
    for (int b = 0; b < BATCH; ++b) {
        float y0 = y[(size_t)b * N + s0];
        float y1 = y[(size_t)b * N + s1];
        float gm = coef * fmaxf(y0 - y1, 0.0f);
        if (gm != 0.0f) atomicAdd(&out[(size_t)b * N + s0], -gm);
    }
}

// ---------------- launch ----------------

extern "C" void kernel_launch(void* const* d_in, const int* in_sizes, int n_in,
                              void* d_out, int out_size, void* d_ws, size_t ws_size,
                              hipStream_t stream) {
    const float* y   = (const float*)d_in[0];   // [B,N]
    const float* gea = (const float*)d_in[2];   // [E]
    const float* dw  = (const float*)d_in[3];   // [E]
    const int*   ei  = (const int*)d_in[4];     // [2,E]

    const int E = in_sizes[2];
    const int N = in_sizes[0] / BATCH;
    const int* ei0 = ei;
    const int* ei1 = ei + E;

    const int K = (N + SBUCKET - 1) >> S_LOG;
    const int Npad = K << S_LOG;

    size_t o_yT     = 0;
    size_t o_rcf    = o_yT     + alignup((size_t)Npad * 16);
    size_t o_counts = o_rcf    + alignup((size_t)E * 8);
    size_t o_base   = o_counts + alignup((size_t)KC * CB * 4);
    size_t o_tot    = o_base   + alignup((size_t)KC * CB * 4);
    size_t o_bb     = o_tot    + alignup((size_t)KC * 4);
    size_t o_pdegp  = o_bb     + alignup((size_t)(KC + 1) * 4);
    size_t o_pout   = o_pdegp  + alignup((size_t)MA * Npad * 4);
    size_t need     = o_pout   + alignup((size_t)MA * BATCH * Npad * 4);

    if (K <= KC && N <= 131071 && ws_size >= need) {
        char* w = (char*)d_ws;
        uint4*    yT     = (uint4*)(w + o_yT);
        uint2*    w0coef = (uint2*)(w + o_rcf);
        unsigned* counts = (unsigned*)(w + o_counts);
        unsigned* base   = (unsigned*)(w + o_base);
        unsigned* tot    = (unsigned*)(w + o_tot);
        unsigned* bb     = (unsigned*)(w + o_bb);
        float*    pdegp  = (float*)(w + o_pdegp);
        float*    pout   = (float*)(w + o_pout);

        int tb = (Npad + 255) / 256;
        count_transpose_kernel<<<CB + tb, 256, 0, stream>>>(ei0, counts, y, yT,
                                                            E, N, Npad);
        scanB1_kernel<<<K, 256, 0, stream>>>(counts, base, tot);
        scanC_kernel<<<1, KC, 0, stream>>>(tot, bb, E, K);
        scatter_kernel<<<CB, 256, 0, stream>>>(ei0, ei1, dw, gea, base, bb,
                                               w0coef, E);
        accum_kernel<<<dim3(K, MA), 256, 0, stream>>>(w0coef, bb, yT,
                                                      pdegp, pout, N, Npad);
        finalize_kernel<<<(N + 255) / 256, 256, 0, stream>>>(
            pdegp, pout, (float*)d_out, N, Npad);
    } else {
        float* deg = (float*)d_ws;
        (void)hipMemsetAsync(deg, 0, (size_t)N * sizeof(float), stream);
        fill_one_kernel<<<(out_size + 255) / 256, 256, 0, stream>>>((float*)d_out, out_size);
        deg_kernel<<<(E + 255) / 256, 256, 0, stream>>>(gea, ei0, deg, E);
        edge_kernel<<<(E + 255) / 256, 256, 0, stream>>>(y, dw, ei0, ei1, deg,
                                                         (float*)d_out, E, N);
    }
}